// Round 18
// baseline (2041.982 us; speedup 1.0000x reference)
//
#include <hip/hip_runtime.h>
#include <math.h>

#define SEQ   1536
#define BATCH 4
#define ROWS  (BATCH*SEQ)   // 6144
#define DM    256
#define NH    8
#define HDIM  32
#define NL    24
#define DFFN  1024
#define OSTR  36            // padded O-park row stride (floats)

// q pre-scale: (1/sqrt(32)) * log2(e)  -> scores arrive in log2 domain
#define QSCALE (0.17677669529663687f * 1.4426950408889634f)

typedef __bf16  bf16x4 __attribute__((ext_vector_type(4)));
typedef __bf16  bf16x8 __attribute__((ext_vector_type(8)));
typedef float   f32x4  __attribute__((ext_vector_type(4)));

__device__ __forceinline__ unsigned short f2bf(float f) {
    union { float f; unsigned int u; } v; v.f = f;
    return (unsigned short)((v.u + 0x7fffu + ((v.u >> 16) & 1u)) >> 16);
}
__device__ __forceinline__ float bf2f(unsigned short u) {
    union { unsigned int i; float f; } v; v.i = ((unsigned int)u) << 16; return v.f;
}
__device__ __forceinline__ float ex2(float x) {
    return __builtin_amdgcn_exp2f(x);   // v_exp_f32: 2^x, exp2(-inf)=0
}

__device__ __forceinline__ void gload16(const void* g, void* l) {
    __builtin_amdgcn_global_load_lds(
        (const __attribute__((address_space(1))) void*)g,
        (__attribute__((address_space(3))) void*)l, 16, 0, 0);
}

// ---------------- fused weight f32 -> bf16 pre-pass (4 segments) ------------
__global__ __launch_bounds__(256) void w2bf4_kernel(
    const float* __restrict__ s0, unsigned short* __restrict__ d0v, int n0,
    const float* __restrict__ s1, unsigned short* __restrict__ d1v, int n1,
    const float* __restrict__ s2, unsigned short* __restrict__ d2v, int n2,
    const float* __restrict__ s3, unsigned short* __restrict__ d3v)
{
    int blk = blockIdx.x;
    const float* src; unsigned short* dst;
    if (blk < n0)                { src = s0; dst = d0v; }
    else if (blk < n0 + n1)      { src = s1; dst = d1v; blk -= n0; }
    else if (blk < n0 + n1 + n2) { src = s2; dst = d2v; blk -= n0 + n1; }
    else                         { src = s3; dst = d3v; blk -= n0 + n1 + n2; }
    int i = (blk * 256 + threadIdx.x) * 8;
    float4 a = *(const float4*)(src + i);
    float4 b = *(const float4*)(src + i + 4);
    union { unsigned short u[8]; uint4 v; } pk;
    pk.u[0] = f2bf(a.x); pk.u[1] = f2bf(a.y); pk.u[2] = f2bf(a.z); pk.u[3] = f2bf(a.w);
    pk.u[4] = f2bf(b.x); pk.u[5] = f2bf(b.y); pk.u[6] = f2bf(b.z); pk.u[7] = f2bf(b.w);
    *(uint4*)(dst + i) = pk.v;
}

// ---------------- positional-embedding add ----------------------------------
__global__ __launch_bounds__(256) void pe_add_kernel(
    const float* __restrict__ x, const float* __restrict__ pe,
    float* __restrict__ h, unsigned short* __restrict__ hb)
{
    int i4  = blockIdx.x * 256 + threadIdx.x;
    int idx = i4 * 4;
    int row = idx >> 8;
    int d   = idx & 255;
    int s   = row % SEQ;
    float4 xv = *(const float4*)(x + idx);
    float4 pv = *(const float4*)(pe + s * DM + d);
    float4 hv;
    hv.x = xv.x + pv.x; hv.y = xv.y + pv.y; hv.z = xv.z + pv.z; hv.w = xv.w + pv.w;
    *(float4*)(h + idx) = hv;
    ushort4 hbv;
    hbv.x = f2bf(hv.x); hbv.y = f2bf(hv.y); hbv.z = f2bf(hv.z); hbv.w = f2bf(hv.w);
    *(ushort4*)(hb + idx) = hbv;
}

// ======================= GEMM v3: 128x64 tile, dbuf, swizzled ================
template<int K, int EPI>
__global__ __launch_bounds__(256) void gemm3(
    const unsigned short* __restrict__ A,
    const unsigned short* __restrict__ W,
    const float* __restrict__ bias,
    unsigned short* __restrict__ outb,
    unsigned short* __restrict__ vT)
{
    __shared__ unsigned short Ash[2][128 * 64];
    __shared__ unsigned short Bsh[2][64 * 64];
    const int m0 = blockIdx.x * 128;
    const int n0 = blockIdx.y * 64;
    const int t  = threadIdx.x;
    const int lane = t & 63;
    const int wv = t >> 6;
    const int wm = wv >> 1, wn = wv & 1;
    const int l15 = lane & 15, l4 = lane >> 4;

    const int ar = lane >> 3;
    const int sx = ((lane & 7) ^ ar) * 8;

    f32x4 acc[4][2];
    #pragma unroll
    for (int i = 0; i < 4; ++i) { acc[i][0] = (f32x4){0,0,0,0}; acc[i][1] = (f32x4){0,0,0,0}; }

    const int NT = K / 64;
    #pragma unroll
    for (int i = 0; i < 4; ++i) {
        int c = wv * 4 + i;
        gload16(&A[(size_t)(m0 + c * 8 + ar) * K + sx], &Ash[0][c * 512]);
    }
    gload16(&W[(size_t)(n0 + wv * 8 + ar) * K + sx],        &Bsh[0][wv * 512]);
    gload16(&W[(size_t)(n0 + (wv + 4) * 8 + ar) * K + sx],  &Bsh[0][(wv + 4) * 512]);
    __syncthreads();

    int cur = 0;
    for (int tt = 0; tt < NT; ++tt) {
        if (tt + 1 < NT) {
            const int k0 = (tt + 1) * 64;
            #pragma unroll
            for (int i = 0; i < 4; ++i) {
                int c = wv * 4 + i;
                gload16(&A[(size_t)(m0 + c * 8 + ar) * K + k0 + sx], &Ash[cur ^ 1][c * 512]);
            }
            gload16(&W[(size_t)(n0 + wv * 8 + ar) * K + k0 + sx],       &Bsh[cur ^ 1][wv * 512]);
            gload16(&W[(size_t)(n0 + (wv + 4) * 8 + ar) * K + k0 + sx], &Bsh[cur ^ 1][(wv + 4) * 512]);
        }
        #pragma unroll
        for (int kk = 0; kk < 2; ++kk) {
            bf16x8 af[4], bfr[2];
            #pragma unroll
            for (int mt = 0; mt < 4; ++mt) {
                int row = wm * 64 + mt * 16 + l15;
                af[mt] = *(const bf16x8*)&Ash[cur][row * 64 + (((kk * 4 + l4) ^ (l15 & 7)) * 8)];
            }
            #pragma unroll
            for (int nt = 0; nt < 2; ++nt) {
                int row = wn * 32 + nt * 16 + l15;
                bfr[nt] = *(const bf16x8*)&Bsh[cur][row * 64 + (((kk * 4 + l4) ^ (l15 & 7)) * 8)];
            }
            #pragma unroll
            for (int mt = 0; mt < 4; ++mt)
                #pragma unroll
                for (int nt = 0; nt < 2; ++nt)
                    acc[mt][nt] = __builtin_amdgcn_mfma_f32_16x16x32_bf16(af[mt], bfr[nt], acc[mt][nt], 0, 0, 0);
        }
        __syncthreads();
        cur ^= 1;
    }

    #pragma unroll
    for (int mt = 0; mt < 4; ++mt)
    #pragma unroll
    for (int nt = 0; nt < 2; ++nt)
    #pragma unroll
    for (int r = 0; r < 4; ++r) {
        int row = m0 + wm * 64 + mt * 16 + l4 * 4 + r;
        int col = n0 + wn * 32 + nt * 16 + l15;
        float val = acc[mt][nt][r] + bias[col];
        if (EPI == 0) {
            if (col < 512) {
                if (col < 256) val *= QSCALE;     // 1/sqrt(HD) * log2(e)
                outb[(size_t)row * 512 + col] = f2bf(val);
            } else {
                int c = col - 512; int hh = c >> 5; int d = c & 31;
                int b = row / SEQ; int s = row - b * SEQ;
                vT[(((size_t)(b * NH + hh)) * HDIM + d) * SEQ + s] = f2bf(val);
            }
        } else {
            float g = 0.5f * val * (1.0f + erff(val * 0.70710678118654752f));
            outb[(size_t)row * DFFN + col] = f2bf(g);
        }
    }
}

// ============ GEMM+LN fused: BM x 256 (full row), dbuf, swizzled =============
template<int K, int BM>
__global__ __launch_bounds__(256) void gemm_ln(
    const unsigned short* __restrict__ A,
    const unsigned short* __restrict__ W,
    const float* __restrict__ bias,
    const float* __restrict__ resid,
    const float* __restrict__ gam, const float* __restrict__ bet,
    float* __restrict__ hout, unsigned short* __restrict__ hbout)
{
    constexpr int MT = BM / 16;
    __shared__ unsigned short Ash[2][BM * 64];
    __shared__ unsigned short Bsh[2][256 * 64];
    __shared__ float red[4][BM][2];
    const int m0 = blockIdx.x * BM;
    const int t  = threadIdx.x;
    const int lane = t & 63;
    const int w  = t >> 6;
    const int l15 = lane & 15, l4 = lane >> 4;
    const int ar = lane >> 3;
    const int sx = ((lane & 7) ^ ar) * 8;

    f32x4 acc[MT][4];
    #pragma unroll
    for (int mt = 0; mt < MT; ++mt)
        #pragma unroll
        for (int nt = 0; nt < 4; ++nt)
            acc[mt][nt] = (f32x4){0,0,0,0};

    const int NT = K / 64;
    if (w < BM / 8)
        gload16(&A[(size_t)(m0 + w * 8 + ar) * K + sx], &Ash[0][w * 512]);
    #pragma unroll
    for (int i = 0; i < 8; ++i) {
        int c = w * 8 + i;
        gload16(&W[(size_t)(c * 8 + ar) * K + sx], &Bsh[0][c * 512]);
    }
    __syncthreads();

    int cur = 0;
    for (int tt = 0; tt < NT; ++tt) {
        if (tt + 1 < NT) {
            const int k0 = (tt + 1) * 64;
            if (w < BM / 8)
                gload16(&A[(size_t)(m0 + w * 8 + ar) * K + k0 + sx], &Ash[cur ^ 1][w * 512]);
            #pragma unroll
            for (int i = 0; i < 8; ++i) {
                int c = w * 8 + i;
                gload16(&W[(size_t)(c * 8 + ar) * K + k0 + sx], &Bsh[cur ^ 1][c * 512]);
            }
        }
        #pragma unroll
        for (int kk = 0; kk < 2; ++kk) {
            bf16x8 af[MT], bfr[4];
            #pragma unroll
            for (int mt = 0; mt < MT; ++mt) {
                int row = mt * 16 + l15;
                af[mt] = *(const bf16x8*)&Ash[cur][row * 64 + (((kk * 4 + l4) ^ (l15 & 7)) * 8)];
            }
            #pragma unroll
            for (int nt = 0; nt < 4; ++nt) {
                int row = w * 64 + nt * 16 + l15;
                bfr[nt] = *(const bf16x8*)&Bsh[cur][row * 64 + (((kk * 4 + l4) ^ (l15 & 7)) * 8)];
            }
            #pragma unroll
            for (int mt = 0; mt < MT; ++mt)
                #pragma unroll
                for (int nt = 0; nt < 4; ++nt)
                    acc[mt][nt] = __builtin_amdgcn_mfma_f32_16x16x32_bf16(af[mt], bfr[nt], acc[mt][nt], 0, 0, 0);
        }
        __syncthreads();
        cur ^= 1;
    }

    float vals[MT][4][4];
    float gc[4], bc[4];
    #pragma unroll
    for (int nt = 0; nt < 4; ++nt) {
        int col = w * 64 + nt * 16 + l15;
        gc[nt] = gam[col];
        bc[nt] = bet[col];
    }
    #pragma unroll
    for (int mt = 0; mt < MT; ++mt)
        #pragma unroll
        for (int r = 0; r < 4; ++r) {
            int rowl = mt * 16 + l4 * 4 + r;
            float s = 0.f, s2 = 0.f;
            #pragma unroll
            for (int nt = 0; nt < 4; ++nt) {
                int col = w * 64 + nt * 16 + l15;
                float v = acc[mt][nt][r] + bias[col]
                        + resid[(size_t)(m0 + rowl) * DM + col];
                vals[mt][nt][r] = v;
                s += v; s2 += v * v;
            }
            s  += __shfl_xor(s, 1);  s2 += __shfl_xor(s2, 1);
            s  += __shfl_xor(s, 2);  s2 += __shfl_xor(s2, 2);
            s  += __shfl_xor(s, 4);  s2 += __shfl_xor(s2, 4);
            s  += __shfl_xor(s, 8);  s2 += __shfl_xor(s2, 8);
            if (l15 == 0) { red[w][rowl][0] = s; red[w][rowl][1] = s2; }
        }
    __syncthreads();

    #pragma unroll
    for (int mt = 0; mt < MT; ++mt)
        #pragma unroll
        for (int r = 0; r < 4; ++r) {
            int rowl = mt * 16 + l4 * 4 + r;
            float tot  = red[0][rowl][0] + red[1][rowl][0] + red[2][rowl][0] + red[3][rowl][0];
            float tot2 = red[0][rowl][1] + red[1][rowl][1] + red[2][rowl][1] + red[3][rowl][1];
            float mean = tot * (1.0f / 256.0f);
            float var  = tot2 * (1.0f / 256.0f) - mean * mean;
            float rstd = rsqrtf(var + 1e-5f);
            size_t base = (size_t)(m0 + rowl) * DM;
            #pragma unroll
            for (int nt = 0; nt < 4; ++nt) {
                int col = w * 64 + nt * 16 + l15;
                float y = (vals[mt][nt][r] - mean) * rstd * gc[nt] + bc[nt];
                hout[base + col]  = y;
                hbout[base + col] = f2bf(y);
            }
        }
}

// ---------------- legacy single-buffer GEMM (f32 weights fallback) ----------
template<int K, int EPI>
__global__ __launch_bounds__(256) void gemm2f(
    const unsigned short* __restrict__ A,
    const float* __restrict__ W,
    const float* __restrict__ bias,
    float* __restrict__ outf,
    unsigned short* __restrict__ outb,
    unsigned short* __restrict__ vT,
    const float* __restrict__ resid)
{
    __shared__ unsigned short Ash[64 * 64];
    __shared__ unsigned short Bsh[64 * 64];
    const int m0 = blockIdx.x * 64;
    const int n0 = blockIdx.y * 64;
    const int t  = threadIdx.x;
    const int lane = t & 63;
    const int wv = t >> 6;
    const int wm = wv >> 1, wn = wv & 1;
    const int l15 = lane & 15, l4 = lane >> 4;
    const int ar = lane >> 3;
    const int ac = (lane & 7) * 8;
    const int c0 = wv, c1 = wv + 4;

    f32x4 acc[2][2];
    #pragma unroll
    for (int i = 0; i < 2; ++i) { acc[i][0] = (f32x4){0,0,0,0}; acc[i][1] = (f32x4){0,0,0,0}; }

    for (int k0 = 0; k0 < K; k0 += 64) {
        gload16(&A[(size_t)(m0 + c0 * 8 + ar) * K + k0 + ac], &Ash[c0 * 512]);
        gload16(&A[(size_t)(m0 + c1 * 8 + ar) * K + k0 + ac], &Ash[c1 * 512]);
        {
            int row = t >> 2, seg = (t & 3) * 16;
            const float* gw = W + (size_t)(n0 + row) * K + k0 + seg;
            float4 w0 = *(const float4*)(gw);
            float4 w1 = *(const float4*)(gw + 4);
            float4 w2 = *(const float4*)(gw + 8);
            float4 w3 = *(const float4*)(gw + 12);
            union { unsigned short u[8]; uint4 v; } p0, p1;
            p0.u[0] = f2bf(w0.x); p0.u[1] = f2bf(w0.y); p0.u[2] = f2bf(w0.z); p0.u[3] = f2bf(w0.w);
            p0.u[4] = f2bf(w1.x); p0.u[5] = f2bf(w1.y); p0.u[6] = f2bf(w1.z); p0.u[7] = f2bf(w1.w);
            p1.u[0] = f2bf(w2.x); p1.u[1] = f2bf(w2.y); p1.u[2] = f2bf(w2.z); p1.u[3] = f2bf(w2.w);
            p1.u[4] = f2bf(w3.x); p1.u[5] = f2bf(w3.y); p1.u[6] = f2bf(w3.z); p1.u[7] = f2bf(w3.w);
            *(uint4*)&Bsh[row * 64 + seg] = p0.v;
            *(uint4*)&Bsh[row * 64 + seg + 8] = p1.v;
        }
        __syncthreads();
        #pragma unroll
        for (int kk = 0; kk < 2; ++kk) {
            bf16x8 af[2], bfr[2];
            #pragma unroll
            for (int mt = 0; mt < 2; ++mt)
                af[mt] = *(const bf16x8*)&Ash[(wm * 32 + mt * 16 + l15) * 64 + kk * 32 + l4 * 8];
            #pragma unroll
            for (int nt = 0; nt < 2; ++nt)
                bfr[nt] = *(const bf16x8*)&Bsh[(wn * 32 + nt * 16 + l15) * 64 + kk * 32 + l4 * 8];
            #pragma unroll
            for (int mt = 0; mt < 2; ++mt)
                #pragma unroll
                for (int nt = 0; nt < 2; ++nt)
                    acc[mt][nt] = __builtin_amdgcn_mfma_f32_16x16x32_bf16(af[mt], bfr[nt], acc[mt][nt], 0, 0, 0);
        }
        __syncthreads();
    }

    #pragma unroll
    for (int mt = 0; mt < 2; ++mt)
    #pragma unroll
    for (int nt = 0; nt < 2; ++nt)
    #pragma unroll
    for (int r = 0; r < 4; ++r) {
        int row = m0 + wm * 32 + mt * 16 + l4 * 4 + r;
        int col = n0 + wn * 32 + nt * 16 + l15;
        float val = acc[mt][nt][r] + bias[col];
        if (EPI == 0) {
            if (col < 512) {
                if (col < 256) val *= QSCALE;
                outb[(size_t)row * 512 + col] = f2bf(val);
            } else {
                int c = col - 512; int hh = c >> 5; int d = c & 31;
                int b = row / SEQ; int s = row - b * SEQ;
                vT[(((size_t)(b * NH + hh)) * HDIM + d) * SEQ + s] = f2bf(val);
            }
        } else if (EPI == 1) {
            outf[(size_t)row * DM + col] = val + resid[(size_t)row * DM + col];
        } else {
            float g = 0.5f * val * (1.0f + erff(val * 0.70710678118654752f));
            outb[(size_t)row * DFFN + col] = f2bf(g);
        }
    }
}

// ---------------- block-causal flash attention v7: KVBLK=128 ----------------
// R7/R15 structure (3 splits, in-LDS combine, exp2 domain) with 128-key tiles:
// halves iteration count & per-tile fixed overhead. QK/softmax in two
// kt-halves to bound live VGPRs. Slow path unchanged (64-step). grid (48,32).
__global__ __launch_bounds__(192) void attn6(
    const unsigned short* __restrict__ qkv,   // [ROWS,512] bf16 (q|k), q scaled
    const unsigned short* __restrict__ vT,    // [B,NH,HDIM,SEQ] bf16
    unsigned short* __restrict__ ob)          // [ROWS,DM] bf16
{
    const int sp   = threadIdx.x >> 6;        // split 0..2
    const int lane = threadIdx.x & 63;
    const int qt = 47 - (int)blockIdx.x;      // long blocks first
    const int bh = blockIdx.y;
    const int b = bh >> 3, h = bh & 7;
    const int l15 = lane & 15, l4 = lane >> 4;
    const int q0 = qt * 32;

    __shared__ unsigned short P[3][2][32 * 128];  // 48 KB; [sp] doubles as O park
    __shared__ float sml[3][96];

    const int kend   = ((q0 + 31) / 3) * 3 + 3;
    const int ntiles = (kend + 127) >> 7;
    const int t0 = (ntiles * sp) / 3;
    const int t1 = (ntiles * (sp + 1)) / 3;
    const bool empty = (t0 >= t1);

    float* Osp = (float*)P[sp];               // 32 x OSTR f32 region

    if (empty) {
        #pragma unroll
        for (int i = 0; i < 18; ++i) Osp[lane + i * 64] = 0.f;
        if (lane < 32) { sml[sp][lane] = 0.f; sml[sp][32 + lane] = 0.f; }
    } else {
        const int kendc = min(t1 * 128, kend);
        const int lim_min = (q0 / 3) * 3 + 3;

        bf16x8 qf[2];
        #pragma unroll
        for (int mt = 0; mt < 2; ++mt)
            qf[mt] = *(const bf16x8*)&qkv[((size_t)(b * SEQ + q0 + mt * 16 + l15)) * 512 + h * 32 + l4 * 8];

        const int sw = (l15 & 7) << 3;
        int lim2[2];
        lim2[0] = ((q0 + l15) / 3) * 3 + 3;
        lim2[1] = ((q0 + 16 + l15) / 3) * 3 + 3;

        float lsum[2] = {0.f, 0.f};
        f32x4 of[2][2];
        const f32x4 zf = (f32x4){0.f, 0.f, 0.f, 0.f};
        of[0][0] = zf; of[0][1] = zf; of[1][0] = zf; of[1][1] = zf;

        bf16x8 kf[8];
        #pragma unroll
        for (int kt = 0; kt < 8; ++kt)
            kf[kt] = *(const bf16x8*)&qkv[((size_t)(b * SEQ + t0 * 128 + kt * 16 + l15)) * 512 + 256 + h * 32 + l4 * 8];

        int pb = 0;
        for (int j0 = t0 * 128; j0 < kendc; j0 += 128) {
            const bool masked = (j0 + 128 > lim_min);

            // ---- QK^T + softmax in two kt-halves (bounds live sf regs) ----
            #pragma unroll
            for (int kh = 0; kh < 2; ++kh) {
                f32x4 sf[2][4];
                #pragma unroll
                for (int mt = 0; mt < 2; ++mt)
                    #pragma unroll
                    for (int kt = 0; kt < 4; ++kt)
                        sf[mt][kt] = __builtin_amdgcn_mfma_f32_16x16x32_bf16(kf[kh * 4 + kt], qf[mt], zf, 0, 0, 0);
                #pragma unroll
                for (int mt = 0; mt < 2; ++mt) {
                    const int rowq = mt * 16 + l15;
                    float ls = 0.f;
                    #pragma unroll
                    for (int kt = 0; kt < 4; ++kt) {
                        const int kc = kh * 4 + kt;        // key chunk 0..7
                        float s0 = sf[mt][kt][0], s1 = sf[mt][kt][1];
                        float s2 = sf[mt][kt][2], s3 = sf[mt][kt][3];
                        if (masked) {
                            const int kb = j0 + kc * 16 + l4 * 4;
                            const int L = lim2[mt];
                            s0 = (kb     < L) ? s0 : -INFINITY;
                            s1 = (kb + 1 < L) ? s1 : -INFINITY;
                            s2 = (kb + 2 < L) ? s2 : -INFINITY;
                            s3 = (kb + 3 < L) ? s3 : -INFINITY;
                        }
                        float p0 = ex2(s0), p1 = ex2(s1);
                        float p2 = ex2(s2), p3 = ex2(s3);
                        ls += (p0 + p1) + (p2 + p3);
                        bf16x4 pk;
                        pk[0] = (__bf16)p0; pk[1] = (__bf16)p1;
                        pk[2] = (__bf16)p2; pk[3] = (__bf16)p3;
                        *(bf16x4*)&P[sp][pb][rowq * 128 + ((kc * 16 + l4 * 4) ^ sw)] = pk;
                    }
                    lsum[mt] += ls;
                }
            }

            // ---- prefetch next K tile (kf consumed), V loads, PV ----------
            const int jn = (j0 + 128 < kendc) ? j0 + 128 : j0;
            bf16x8 kfn[8];
            #pragma unroll
            for (int kt = 0; kt < 8; ++kt)
                kfn[kt] = *(const bf16x8*)&qkv[((size_t)(b * SEQ + jn + kt * 16 + l15)) * 512 + 256 + h * 32 + l4 * 8];
            bf16x8 vf[2][4];
            #pragma unroll
            for (int dh = 0; dh < 2; ++dh)
                #pragma unroll
                for (int ks = 0; ks < 4; ++ks)
                    vf[dh][ks] = *(const bf16x8*)&vT[(((size_t)(b * NH + h)) * HDIM + dh * 16 + l15) * SEQ + j0 + ks * 32 + l4 * 8];

            bf16x8 pf[2][4];
            #pragma unroll
            for (int mt = 0; mt < 2; ++mt) {
                int row = mt * 16 + l15;
                #pragma unroll
                for (int ks = 0; ks < 4; ++ks)
                    pf[mt][ks] = *(const bf16x8*)&P[sp][pb][row * 128 + ((ks * 32 + l4 * 8) ^ sw)];
            }
            #pragma unroll
            for (int mt = 0; mt < 2; ++mt)
                #pragma unroll
                for (int dh = 0; dh < 2; ++dh) {
                    f32x4 o = of[mt][dh];
                    #pragma unroll
                    for (int ks = 0; ks < 4; ++ks)
                        o = __builtin_amdgcn_mfma_f32_16x16x32_bf16(pf[mt][ks], vf[dh][ks], o, 0, 0, 0);
                    of[mt][dh] = o;
                }
            #pragma unroll
            for (int kt = 0; kt < 8; ++kt) kf[kt] = kfn[kt];
            pb ^= 1;
        }

        int bad = (lsum[0] > 1.0e30f || lsum[1] > 1.0e30f) ? 1 : 0;
        if (__any(bad)) {
            // ---- exact safe re-run with online max (never taken normally) --
            // 64-step loop, uses P[sp][1] region with 64-short row stride.
            int lim[2][4];
            float mrow[2][4], lsumO[2][4];
            #pragma unroll
            for (int mt = 0; mt < 2; ++mt) {
                of[mt][0] = zf; of[mt][1] = zf;
                #pragma unroll
                for (int r = 0; r < 4; ++r) {
                    mrow[mt][r] = -INFINITY; lsumO[mt][r] = 0.f;
                    int q = q0 + mt * 16 + l4 * 4 + r;
                    lim[mt][r] = (q / 3) * 3 + 3;
                }
            }
            for (int j0 = t0 * 128; j0 < kendc; j0 += 64) {
                bf16x8 kfs[4];
                #pragma unroll
                for (int kt = 0; kt < 4; ++kt)
                    kfs[kt] = *(const bf16x8*)&qkv[((size_t)(b * SEQ + j0 + kt * 16 + l15)) * 512 + 256 + h * 32 + l4 * 8];
                f32x4 sf[2][4];
                #pragma unroll
                for (int mt = 0; mt < 2; ++mt)
                    #pragma unroll
                    for (int kt = 0; kt < 4; ++kt)
                        sf[mt][kt] = __builtin_amdgcn_mfma_f32_16x16x32_bf16(qf[mt], kfs[kt], zf, 0, 0, 0);
                #pragma unroll
                for (int mt = 0; mt < 2; ++mt) {
                    float alpha[4];
                    #pragma unroll
                    for (int r = 0; r < 4; ++r) {
                        const int L = lim[mt][r]; int jb = j0 + l15;
                        float s0 = (jb      < L) ? sf[mt][0][r] : -INFINITY;
                        float s1 = (jb + 16 < L) ? sf[mt][1][r] : -INFINITY;
                        float s2 = (jb + 32 < L) ? sf[mt][2][r] : -INFINITY;
                        float s3 = (jb + 48 < L) ? sf[mt][3][r] : -INFINITY;
                        float tm = fmaxf(fmaxf(s0, s1), fmaxf(s2, s3));
                        tm = fmaxf(tm, __shfl_xor(tm, 1));
                        tm = fmaxf(tm, __shfl_xor(tm, 2));
                        tm = fmaxf(tm, __shfl_xor(tm, 4));
                        tm = fmaxf(tm, __shfl_xor(tm, 8));
                        float mn = fmaxf(mrow[mt][r], tm);
                        float a  = ex2(mrow[mt][r] - mn);
                        mrow[mt][r] = mn;
                        float p0 = ex2(s0 - mn), p1 = ex2(s1 - mn);
                        float p2 = ex2(s2 - mn), p3 = ex2(s3 - mn);
                        int row = mt * 16 + l4 * 4 + r;
                        int swo = (row & 7) << 3;
                        P[sp][1][(row * 64 +      l15) ^ swo] = f2bf(p0);
                        P[sp][1][(row * 64 + 16 + l15) ^ swo] = f2bf(p1);
                        P[sp][1][(row * 64 + 32 + l15) ^ swo] = f2bf(p2);
                        P[sp][1][(row * 64 + 48 + l15) ^ swo] = f2bf(p3);
                        lsumO[mt][r] = lsumO[mt][r] * a + (p0 + p1) + (p2 + p3);
                        alpha[r] = a;
                    }
                    f32x4 av = (f32x4){alpha[0], alpha[1], alpha[2], alpha[3]};
                    of[mt][0] *= av; of[mt][1] *= av;
                }
                bf16x8 pf[2][2], vf[2][2];
                #pragma unroll
                for (int mt = 0; mt < 2; ++mt) {
                    int row = mt * 16 + l15;
                    int swo = (row & 7) << 3;
                    #pragma unroll
                    for (int ks = 0; ks < 2; ++ks)
                        pf[mt][ks] = *(const bf16x8*)&P[sp][1][(row * 64 + ks * 32 + l4 * 8) ^ swo];
                }
                #pragma unroll
                for (int dh = 0; dh < 2; ++dh)
                    #pragma unroll
                    for (int ks = 0; ks < 2; ++ks)
                        vf[dh][ks] = *(const bf16x8*)&vT[(((size_t)(b * NH + h)) * HDIM + dh * 16 + l15) * SEQ + j0 + ks * 32 + l4 * 8];
                #pragma unroll
                for (int mt = 0; mt < 2; ++mt)
                    #pragma unroll
                    for (int dh = 0; dh < 2; ++dh) {
                        of[mt][dh] = __builtin_amdgcn_mfma_f32_16x16x32_bf16(pf[mt][0], vf[dh][0], of[mt][dh], 0, 0, 0);
                        of[mt][dh] = __builtin_amdgcn_mfma_f32_16x16x32_bf16(pf[mt][1], vf[dh][1], of[mt][dh], 0, 0, 0);
                    }
            }
            #pragma unroll
            for (int mt = 0; mt < 2; ++mt)
                #pragma unroll
                for (int r = 0; r < 4; ++r) {
                    float s = lsumO[mt][r];
                    s += __shfl_xor(s, 1);
                    s += __shfl_xor(s, 2);
                    s += __shfl_xor(s, 4);
                    s += __shfl_xor(s, 8);
                    lsumO[mt][r] = s;
                }
            #pragma unroll
            for (int mt = 0; mt < 2; ++mt)
                #pragma unroll
                for (int dh = 0; dh < 2; ++dh)
                    #pragma unroll
                    for (int r = 0; r < 4; ++r)
                        Osp[(mt * 16 + l4 * 4 + r) * OSTR + dh * 16 + l15] = of[mt][dh][r];
            if (l15 == 0) {
                #pragma unroll
                for (int mt = 0; mt < 2; ++mt)
                    #pragma unroll
                    for (int r = 0; r < 4; ++r) {
                        int row = mt * 16 + l4 * 4 + r;
                        sml[sp][row]      = mrow[mt][r];
                        sml[sp][32 + row] = lsumO[mt][r];
                    }
            }
        } else {
            // ---- fast-path finalize: reduce lane-partial lsum, park O -------
            #pragma unroll
            for (int mt = 0; mt < 2; ++mt) {
                float s = lsum[mt];
                s += __shfl_xor(s, 16);
                s += __shfl_xor(s, 32);
                lsum[mt] = s;
            }
            #pragma unroll
            for (int mt = 0; mt < 2; ++mt)
                #pragma unroll
                for (int dh = 0; dh < 2; ++dh)
                    #pragma unroll
                    for (int r = 0; r < 4; ++r)
                        Osp[(mt * 16 + l4 * 4 + r) * OSTR + dh * 16 + l15] = of[mt][dh][r];
            if (lane < 32) sml[sp][lane] = 0.f;
            if (l4 == 0) {
                sml[sp][32 + l15]      = lsum[0];
                sml[sp][32 + 16 + l15] = lsum[1];
            }
        }
    }

    __syncthreads();

    // ---------------- in-block combine + normalize + write ------------------
    const int t = threadIdx.x;
    if (t < 128) {
        const int row = t >> 2;
        const int seg = (t & 3) * 8;
        float m0 = sml[0][row], l0 = sml[0][32 + row];
        float m1 = sml[1][row], l1 = sml[1][32 + row];
        float m2 = sml[2][row], l2 = sml[2][32 + row];
        float mt = fmaxf(fmaxf(m0, m1), m2);
        float w0 = ex2(m0 - mt), w1 = ex2(m1 - mt), w2 = ex2(m2 - mt);
        float inv = 1.0f / (w0 * l0 + w1 * l1 + w2 * l2);
        const float* O0 = (const float*)P[0];
        const float* O1 = (const float*)P[1];
        const float* O2 = (const float*)P[2];
        union { unsigned short u[8]; uint4 v; } pk;
        #pragma unroll
        for (int j = 0; j < 8; ++j) {
            int idx = row * OSTR + seg + j;
            pk.u[j] = f2bf((w0 * O0[idx] + w1 * O1[idx] + w2 * O2[idx]) * inv);
        }
        *(uint4*)&ob[((size_t)(b * SEQ + q0 + row)) * DM + h * 32 + seg] = pk.v;
    }
}

// ---------------- LayerNorm over D=256 (fallback path only) -----------------
__global__ __launch_bounds__(256) void ln_kernel(
    const float* __restrict__ rin,
    const float* __restrict__ gam, const float* __restrict__ bet,
    float* __restrict__ hout, unsigned short* __restrict__ hbout)
{
    int wv = threadIdx.x >> 6, lane = threadIdx.x & 63;
    int row = blockIdx.x * 4 + wv;
    float4 x = *(const float4*)(rin + (size_t)row * DM + lane * 4);
    float s = x.x + x.y + x.z + x.w;
    #pragma unroll
    for (int m = 1; m < 64; m <<= 1) s += __shfl_xor(s, m);
    float mean = s * (1.0f / 256.0f);
    float d0 = x.x - mean, d1 = x.y - mean, d2 = x.z - mean, d3 = x.w - mean;
    float q = d0 * d0 + d1 * d1 + d2 * d2 + d3 * d3;
    #pragma unroll
    for (int m = 1; m < 64; m <<= 1) q += __shfl_xor(q, m);
    float rstd = rsqrtf(q * (1.0f / 256.0f) + 1e-5f);
    float4 g = *(const float4*)(gam + lane * 4);
    float4 b = *(const float4*)(bet + lane * 4);
    float4 y;
    y.x = d0 * rstd * g.x + b.x;
    y.y = d1 * rstd * g.y + b.y;
    y.z = d2 * rstd * g.z + b.z;
    y.w = d3 * rstd * g.w + b.w;
    *(float4*)(hout + (size_t)row * DM + lane * 4) = y;
    ushort4 hb4;
    hb4.x = f2bf(y.x); hb4.y = f2bf(y.y); hb4.z = f2bf(y.z); hb4.w = f2bf(y.w);
    *(ushort4*)(hbout + (size_t)row * DM + lane * 4) = hb4;
}

extern "C" void kernel_launch(void* const* d_in, const int* in_sizes, int n_in,
                              void* d_out, int out_size, void* d_ws, size_t ws_size,
                              hipStream_t stream) {
    const float* x    = (const float*)d_in[0];
    const float* pe   = (const float*)d_in[1];
    const float* Wqkv = (const float*)d_in[2];
    const float* bqkv = (const float*)d_in[3];
    const float* Wo   = (const float*)d_in[4];
    const float* bo   = (const float*)d_in[5];
    const float* W1   = (const float*)d_in[6];
    const float* b1   = (const float*)d_in[7];
    const float* W2   = (const float*)d_in[8];
    const float* b2   = (const float*)d_in[9];
    const float* ln1g = (const float*)d_in[10];
    const float* ln1b = (const float*)d_in[11];
    const float* ln2g = (const float*)d_in[12];
    const float* ln2b = (const float*)d_in[13];
    float* out = (float*)d_out;

    char* ws = (char*)d_ws;
    float*          h    = (float*)(ws + 0);                    // 6,291,456
    unsigned short* hb   = (unsigned short*)(ws + 6291456);     // 3,145,728
    unsigned short* qkvb = (unsigned short*)(ws + 9437184);     // 6,291,456
    unsigned short* vT   = (unsigned short*)(ws + 15728640);    // 3,145,728
    unsigned short* ob   = (unsigned short*)(ws + 18874368);    // 3,145,728
    float*          rbuf = (float*)(ws + 22020096);             // 6,291,456
    unsigned short* f1b  = (unsigned short*)(ws + 28311552);    // 12,582,912 -> 40,894,464
    unsigned short* WqkvB = (unsigned short*)(ws + 40894464);
    unsigned short* WoB   = (unsigned short*)(ws + 50331648);
    unsigned short* W1B   = (unsigned short*)(ws + 53477376);
    unsigned short* W2B   = (unsigned short*)(ws + 66060288);   // -> 78,643,200

    const bool bw = ws_size >= 78643200u;

    if (bw) {
        w2bf4_kernel<<<9216, 256, 0, stream>>>(
            Wqkv, WqkvB, 2304, Wo, WoB, 768, W1, W1B, 3072, W2, W2B);
    }

    pe_add_kernel<<<1536, 256, 0, stream>>>(x, pe, h, hb);

    for (int l = 0; l < NL; ++l) {
        float* hdst = (l == NL - 1) ? out : h;
        if (bw) {
            gemm3<256, 0><<<dim3(48, 12), 256, 0, stream>>>(
                hb, WqkvB + (size_t)l * 768 * 256, bqkv + l * 768, qkvb, vT);
            attn6<<<dim3(48, 32), 192, 0, stream>>>(qkvb, vT, ob);
            gemm_ln<256, 16><<<384, 256, 0, stream>>>(
                ob, WoB + (size_t)l * 256 * 256, bo + l * 256,
                h, ln1g + l * 256, ln1b + l * 256, h, hb);
            gemm3<256, 2><<<dim3(48, 16), 256, 0, stream>>>(
                hb, W1B + (size_t)l * 1024 * 256, b1 + l * 1024, f1b, nullptr);
            gemm_ln<1024, 16><<<384, 256, 0, stream>>>(
                f1b, W2B + (size_t)l * 256 * 1024, b2 + l * 256,
                h, ln2g + l * 256, ln2b + l * 256, hdst, hb);
        } else {
            gemm2f<256, 0><<<dim3(96, 12), 256, 0, stream>>>(
                hb, Wqkv + (size_t)l * 768 * 256, bqkv + l * 768, nullptr, qkvb, vT, nullptr);
            attn6<<<dim3(48, 32), 192, 0, stream>>>(qkvb, vT, ob);
            gemm2f<256, 1><<<dim3(96, 4), 256, 0, stream>>>(
                ob, Wo + (size_t)l * 256 * 256, bo + l * 256, rbuf, nullptr, nullptr, h);
            ln_kernel<<<1536, 256, 0, stream>>>(rbuf, ln1g + l * 256, ln1b + l * 256, h, hb);
            gemm2f<256, 2><<<dim3(96, 16), 256, 0, stream>>>(
                hb, W1 + (size_t)l * 1024 * 256, b1 + l * 1024, nullptr, f1b, nullptr, nullptr);
            gemm2f<1024, 1><<<dim3(96, 4), 256, 0, stream>>>(
                f1b, W2 + (size_t)l * 256 * 1024, b2 + l * 256, rbuf, nullptr, nullptr, h);
            ln_kernel<<<1536, 256, 0, stream>>>(rbuf, ln2g + l * 256, ln2b + l * 256, hdst, hb);
        }
    }
}

// Round 19
// 1951.261 us; speedup vs baseline: 1.0465x; 1.0465x over previous
//
#include <hip/hip_runtime.h>
#include <math.h>

#define SEQ   1536
#define BATCH 4
#define ROWS  (BATCH*SEQ)   // 6144
#define DM    256
#define NH    8
#define HDIM  32
#define NL    24
#define DFFN  1024
#define OSTR  36            // padded O-park row stride (floats)

// q pre-scale: (1/sqrt(32)) * log2(e)  -> scores arrive in log2 domain
#define QSCALE (0.17677669529663687f * 1.4426950408889634f)

typedef __bf16  bf16x4 __attribute__((ext_vector_type(4)));
typedef __bf16  bf16x8 __attribute__((ext_vector_type(8)));
typedef float   f32x4  __attribute__((ext_vector_type(4)));

__device__ __forceinline__ unsigned short f2bf(float f) {
    union { float f; unsigned int u; } v; v.f = f;
    return (unsigned short)((v.u + 0x7fffu + ((v.u >> 16) & 1u)) >> 16);
}
__device__ __forceinline__ float bf2f(unsigned short u) {
    union { unsigned int i; float f; } v; v.i = ((unsigned int)u) << 16; return v.f;
}
__device__ __forceinline__ float ex2(float x) {
    return __builtin_amdgcn_exp2f(x);   // v_exp_f32: 2^x, exp2(-inf)=0
}

__device__ __forceinline__ void gload16(const void* g, void* l) {
    __builtin_amdgcn_global_load_lds(
        (const __attribute__((address_space(1))) void*)g,
        (__attribute__((address_space(3))) void*)l, 16, 0, 0);
}

// ---------------- fused weight f32 -> bf16 pre-pass (4 segments) ------------
__global__ __launch_bounds__(256) void w2bf4_kernel(
    const float* __restrict__ s0, unsigned short* __restrict__ d0v, int n0,
    const float* __restrict__ s1, unsigned short* __restrict__ d1v, int n1,
    const float* __restrict__ s2, unsigned short* __restrict__ d2v, int n2,
    const float* __restrict__ s3, unsigned short* __restrict__ d3v)
{
    int blk = blockIdx.x;
    const float* src; unsigned short* dst;
    if (blk < n0)                { src = s0; dst = d0v; }
    else if (blk < n0 + n1)      { src = s1; dst = d1v; blk -= n0; }
    else if (blk < n0 + n1 + n2) { src = s2; dst = d2v; blk -= n0 + n1; }
    else                         { src = s3; dst = d3v; blk -= n0 + n1 + n2; }
    int i = (blk * 256 + threadIdx.x) * 8;
    float4 a = *(const float4*)(src + i);
    float4 b = *(const float4*)(src + i + 4);
    union { unsigned short u[8]; uint4 v; } pk;
    pk.u[0] = f2bf(a.x); pk.u[1] = f2bf(a.y); pk.u[2] = f2bf(a.z); pk.u[3] = f2bf(a.w);
    pk.u[4] = f2bf(b.x); pk.u[5] = f2bf(b.y); pk.u[6] = f2bf(b.z); pk.u[7] = f2bf(b.w);
    *(uint4*)(dst + i) = pk.v;
}

// ---------------- positional-embedding add ----------------------------------
__global__ __launch_bounds__(256) void pe_add_kernel(
    const float* __restrict__ x, const float* __restrict__ pe,
    float* __restrict__ h, unsigned short* __restrict__ hb)
{
    int i4  = blockIdx.x * 256 + threadIdx.x;
    int idx = i4 * 4;
    int row = idx >> 8;
    int d   = idx & 255;
    int s   = row % SEQ;
    float4 xv = *(const float4*)(x + idx);
    float4 pv = *(const float4*)(pe + s * DM + d);
    float4 hv;
    hv.x = xv.x + pv.x; hv.y = xv.y + pv.y; hv.z = xv.z + pv.z; hv.w = xv.w + pv.w;
    *(float4*)(h + idx) = hv;
    ushort4 hbv;
    hbv.x = f2bf(hv.x); hbv.y = f2bf(hv.y); hbv.z = f2bf(hv.z); hbv.w = f2bf(hv.w);
    *(ushort4*)(hb + idx) = hbv;
}

// ======================= GEMM v3: 128x64 tile, dbuf, swizzled ================
template<int K, int EPI>
__global__ __launch_bounds__(256) void gemm3(
    const unsigned short* __restrict__ A,
    const unsigned short* __restrict__ W,
    const float* __restrict__ bias,
    unsigned short* __restrict__ outb,
    unsigned short* __restrict__ vT)
{
    __shared__ unsigned short Ash[2][128 * 64];
    __shared__ unsigned short Bsh[2][64 * 64];
    const int m0 = blockIdx.x * 128;
    const int n0 = blockIdx.y * 64;
    const int t  = threadIdx.x;
    const int lane = t & 63;
    const int wv = t >> 6;
    const int wm = wv >> 1, wn = wv & 1;
    const int l15 = lane & 15, l4 = lane >> 4;

    const int ar = lane >> 3;
    const int sx = ((lane & 7) ^ ar) * 8;

    f32x4 acc[4][2];
    #pragma unroll
    for (int i = 0; i < 4; ++i) { acc[i][0] = (f32x4){0,0,0,0}; acc[i][1] = (f32x4){0,0,0,0}; }

    const int NT = K / 64;
    #pragma unroll
    for (int i = 0; i < 4; ++i) {
        int c = wv * 4 + i;
        gload16(&A[(size_t)(m0 + c * 8 + ar) * K + sx], &Ash[0][c * 512]);
    }
    gload16(&W[(size_t)(n0 + wv * 8 + ar) * K + sx],        &Bsh[0][wv * 512]);
    gload16(&W[(size_t)(n0 + (wv + 4) * 8 + ar) * K + sx],  &Bsh[0][(wv + 4) * 512]);
    __syncthreads();

    int cur = 0;
    for (int tt = 0; tt < NT; ++tt) {
        if (tt + 1 < NT) {
            const int k0 = (tt + 1) * 64;
            #pragma unroll
            for (int i = 0; i < 4; ++i) {
                int c = wv * 4 + i;
                gload16(&A[(size_t)(m0 + c * 8 + ar) * K + k0 + sx], &Ash[cur ^ 1][c * 512]);
            }
            gload16(&W[(size_t)(n0 + wv * 8 + ar) * K + k0 + sx],       &Bsh[cur ^ 1][wv * 512]);
            gload16(&W[(size_t)(n0 + (wv + 4) * 8 + ar) * K + k0 + sx], &Bsh[cur ^ 1][(wv + 4) * 512]);
        }
        #pragma unroll
        for (int kk = 0; kk < 2; ++kk) {
            bf16x8 af[4], bfr[2];
            #pragma unroll
            for (int mt = 0; mt < 4; ++mt) {
                int row = wm * 64 + mt * 16 + l15;
                af[mt] = *(const bf16x8*)&Ash[cur][row * 64 + (((kk * 4 + l4) ^ (l15 & 7)) * 8)];
            }
            #pragma unroll
            for (int nt = 0; nt < 2; ++nt) {
                int row = wn * 32 + nt * 16 + l15;
                bfr[nt] = *(const bf16x8*)&Bsh[cur][row * 64 + (((kk * 4 + l4) ^ (l15 & 7)) * 8)];
            }
            #pragma unroll
            for (int mt = 0; mt < 4; ++mt)
                #pragma unroll
                for (int nt = 0; nt < 2; ++nt)
                    acc[mt][nt] = __builtin_amdgcn_mfma_f32_16x16x32_bf16(af[mt], bfr[nt], acc[mt][nt], 0, 0, 0);
        }
        __syncthreads();
        cur ^= 1;
    }

    #pragma unroll
    for (int mt = 0; mt < 4; ++mt)
    #pragma unroll
    for (int nt = 0; nt < 2; ++nt)
    #pragma unroll
    for (int r = 0; r < 4; ++r) {
        int row = m0 + wm * 64 + mt * 16 + l4 * 4 + r;
        int col = n0 + wn * 32 + nt * 16 + l15;
        float val = acc[mt][nt][r] + bias[col];
        if (EPI == 0) {
            if (col < 512) {
                if (col < 256) val *= QSCALE;     // 1/sqrt(HD) * log2(e)
                outb[(size_t)row * 512 + col] = f2bf(val);
            } else {
                int c = col - 512; int hh = c >> 5; int d = c & 31;
                int b = row / SEQ; int s = row - b * SEQ;
                vT[(((size_t)(b * NH + hh)) * HDIM + d) * SEQ + s] = f2bf(val);
            }
        } else {
            float g = 0.5f * val * (1.0f + erff(val * 0.70710678118654752f));
            outb[(size_t)row * DFFN + col] = f2bf(g);
        }
    }
}

// ============ GEMM+LN fused: BM x 256 (full row), dbuf, swizzled =============
template<int K, int BM>
__global__ __launch_bounds__(256) void gemm_ln(
    const unsigned short* __restrict__ A,
    const unsigned short* __restrict__ W,
    const float* __restrict__ bias,
    const float* __restrict__ resid,
    const float* __restrict__ gam, const float* __restrict__ bet,
    float* __restrict__ hout, unsigned short* __restrict__ hbout)
{
    constexpr int MT = BM / 16;
    __shared__ unsigned short Ash[2][BM * 64];
    __shared__ unsigned short Bsh[2][256 * 64];
    __shared__ float red[4][BM][2];
    const int m0 = blockIdx.x * BM;
    const int t  = threadIdx.x;
    const int lane = t & 63;
    const int w  = t >> 6;
    const int l15 = lane & 15, l4 = lane >> 4;
    const int ar = lane >> 3;
    const int sx = ((lane & 7) ^ ar) * 8;

    f32x4 acc[MT][4];
    #pragma unroll
    for (int mt = 0; mt < MT; ++mt)
        #pragma unroll
        for (int nt = 0; nt < 4; ++nt)
            acc[mt][nt] = (f32x4){0,0,0,0};

    const int NT = K / 64;
    if (w < BM / 8)
        gload16(&A[(size_t)(m0 + w * 8 + ar) * K + sx], &Ash[0][w * 512]);
    #pragma unroll
    for (int i = 0; i < 8; ++i) {
        int c = w * 8 + i;
        gload16(&W[(size_t)(c * 8 + ar) * K + sx], &Bsh[0][c * 512]);
    }
    __syncthreads();

    int cur = 0;
    for (int tt = 0; tt < NT; ++tt) {
        if (tt + 1 < NT) {
            const int k0 = (tt + 1) * 64;
            if (w < BM / 8)
                gload16(&A[(size_t)(m0 + w * 8 + ar) * K + k0 + sx], &Ash[cur ^ 1][w * 512]);
            #pragma unroll
            for (int i = 0; i < 8; ++i) {
                int c = w * 8 + i;
                gload16(&W[(size_t)(c * 8 + ar) * K + k0 + sx], &Bsh[cur ^ 1][c * 512]);
            }
        }
        #pragma unroll
        for (int kk = 0; kk < 2; ++kk) {
            bf16x8 af[MT], bfr[4];
            #pragma unroll
            for (int mt = 0; mt < MT; ++mt) {
                int row = mt * 16 + l15;
                af[mt] = *(const bf16x8*)&Ash[cur][row * 64 + (((kk * 4 + l4) ^ (l15 & 7)) * 8)];
            }
            #pragma unroll
            for (int nt = 0; nt < 4; ++nt) {
                int row = w * 64 + nt * 16 + l15;
                bfr[nt] = *(const bf16x8*)&Bsh[cur][row * 64 + (((kk * 4 + l4) ^ (l15 & 7)) * 8)];
            }
            #pragma unroll
            for (int mt = 0; mt < MT; ++mt)
                #pragma unroll
                for (int nt = 0; nt < 4; ++nt)
                    acc[mt][nt] = __builtin_amdgcn_mfma_f32_16x16x32_bf16(af[mt], bfr[nt], acc[mt][nt], 0, 0, 0);
        }
        __syncthreads();
        cur ^= 1;
    }

    float vals[MT][4][4];
    float gc[4], bc[4];
    #pragma unroll
    for (int nt = 0; nt < 4; ++nt) {
        int col = w * 64 + nt * 16 + l15;
        gc[nt] = gam[col];
        bc[nt] = bet[col];
    }
    #pragma unroll
    for (int mt = 0; mt < MT; ++mt)
        #pragma unroll
        for (int r = 0; r < 4; ++r) {
            int rowl = mt * 16 + l4 * 4 + r;
            float s = 0.f, s2 = 0.f;
            #pragma unroll
            for (int nt = 0; nt < 4; ++nt) {
                int col = w * 64 + nt * 16 + l15;
                float v = acc[mt][nt][r] + bias[col]
                        + resid[(size_t)(m0 + rowl) * DM + col];
                vals[mt][nt][r] = v;
                s += v; s2 += v * v;
            }
            s  += __shfl_xor(s, 1);  s2 += __shfl_xor(s2, 1);
            s  += __shfl_xor(s, 2);  s2 += __shfl_xor(s2, 2);
            s  += __shfl_xor(s, 4);  s2 += __shfl_xor(s2, 4);
            s  += __shfl_xor(s, 8);  s2 += __shfl_xor(s2, 8);
            if (l15 == 0) { red[w][rowl][0] = s; red[w][rowl][1] = s2; }
        }
    __syncthreads();

    #pragma unroll
    for (int mt = 0; mt < MT; ++mt)
        #pragma unroll
        for (int r = 0; r < 4; ++r) {
            int rowl = mt * 16 + l4 * 4 + r;
            float tot  = red[0][rowl][0] + red[1][rowl][0] + red[2][rowl][0] + red[3][rowl][0];
            float tot2 = red[0][rowl][1] + red[1][rowl][1] + red[2][rowl][1] + red[3][rowl][1];
            float mean = tot * (1.0f / 256.0f);
            float var  = tot2 * (1.0f / 256.0f) - mean * mean;
            float rstd = rsqrtf(var + 1e-5f);
            size_t base = (size_t)(m0 + rowl) * DM;
            #pragma unroll
            for (int nt = 0; nt < 4; ++nt) {
                int col = w * 64 + nt * 16 + l15;
                float y = (vals[mt][nt][r] - mean) * rstd * gc[nt] + bc[nt];
                hout[base + col]  = y;
                hbout[base + col] = f2bf(y);
            }
        }
}

// ---------------- legacy single-buffer GEMM (f32 weights fallback) ----------
template<int K, int EPI>
__global__ __launch_bounds__(256) void gemm2f(
    const unsigned short* __restrict__ A,
    const float* __restrict__ W,
    const float* __restrict__ bias,
    float* __restrict__ outf,
    unsigned short* __restrict__ outb,
    unsigned short* __restrict__ vT,
    const float* __restrict__ resid)
{
    __shared__ unsigned short Ash[64 * 64];
    __shared__ unsigned short Bsh[64 * 64];
    const int m0 = blockIdx.x * 64;
    const int n0 = blockIdx.y * 64;
    const int t  = threadIdx.x;
    const int lane = t & 63;
    const int wv = t >> 6;
    const int wm = wv >> 1, wn = wv & 1;
    const int l15 = lane & 15, l4 = lane >> 4;
    const int ar = lane >> 3;
    const int ac = (lane & 7) * 8;
    const int c0 = wv, c1 = wv + 4;

    f32x4 acc[2][2];
    #pragma unroll
    for (int i = 0; i < 2; ++i) { acc[i][0] = (f32x4){0,0,0,0}; acc[i][1] = (f32x4){0,0,0,0}; }

    for (int k0 = 0; k0 < K; k0 += 64) {
        gload16(&A[(size_t)(m0 + c0 * 8 + ar) * K + k0 + ac], &Ash[c0 * 512]);
        gload16(&A[(size_t)(m0 + c1 * 8 + ar) * K + k0 + ac], &Ash[c1 * 512]);
        {
            int row = t >> 2, seg = (t & 3) * 16;
            const float* gw = W + (size_t)(n0 + row) * K + k0 + seg;
            float4 w0 = *(const float4*)(gw);
            float4 w1 = *(const float4*)(gw + 4);
            float4 w2 = *(const float4*)(gw + 8);
            float4 w3 = *(const float4*)(gw + 12);
            union { unsigned short u[8]; uint4 v; } p0, p1;
            p0.u[0] = f2bf(w0.x); p0.u[1] = f2bf(w0.y); p0.u[2] = f2bf(w0.z); p0.u[3] = f2bf(w0.w);
            p0.u[4] = f2bf(w1.x); p0.u[5] = f2bf(w1.y); p0.u[6] = f2bf(w1.z); p0.u[7] = f2bf(w1.w);
            p1.u[0] = f2bf(w2.x); p1.u[1] = f2bf(w2.y); p1.u[2] = f2bf(w2.z); p1.u[3] = f2bf(w2.w);
            p1.u[4] = f2bf(w3.x); p1.u[5] = f2bf(w3.y); p1.u[6] = f2bf(w3.z); p1.u[7] = f2bf(w3.w);
            *(uint4*)&Bsh[row * 64 + seg] = p0.v;
            *(uint4*)&Bsh[row * 64 + seg + 8] = p1.v;
        }
        __syncthreads();
        #pragma unroll
        for (int kk = 0; kk < 2; ++kk) {
            bf16x8 af[2], bfr[2];
            #pragma unroll
            for (int mt = 0; mt < 2; ++mt)
                af[mt] = *(const bf16x8*)&Ash[(wm * 32 + mt * 16 + l15) * 64 + kk * 32 + l4 * 8];
            #pragma unroll
            for (int nt = 0; nt < 2; ++nt)
                bfr[nt] = *(const bf16x8*)&Bsh[(wn * 32 + nt * 16 + l15) * 64 + kk * 32 + l4 * 8];
            #pragma unroll
            for (int mt = 0; mt < 2; ++mt)
                #pragma unroll
                for (int nt = 0; nt < 2; ++nt)
                    acc[mt][nt] = __builtin_amdgcn_mfma_f32_16x16x32_bf16(af[mt], bfr[nt], acc[mt][nt], 0, 0, 0);
        }
        __syncthreads();
    }

    #pragma unroll
    for (int mt = 0; mt < 2; ++mt)
    #pragma unroll
    for (int nt = 0; nt < 2; ++nt)
    #pragma unroll
    for (int r = 0; r < 4; ++r) {
        int row = m0 + wm * 32 + mt * 16 + l4 * 4 + r;
        int col = n0 + wn * 32 + nt * 16 + l15;
        float val = acc[mt][nt][r] + bias[col];
        if (EPI == 0) {
            if (col < 512) {
                if (col < 256) val *= QSCALE;
                outb[(size_t)row * 512 + col] = f2bf(val);
            } else {
                int c = col - 512; int hh = c >> 5; int d = c & 31;
                int b = row / SEQ; int s = row - b * SEQ;
                vT[(((size_t)(b * NH + hh)) * HDIM + d) * SEQ + s] = f2bf(val);
            }
        } else if (EPI == 1) {
            outf[(size_t)row * DM + col] = val + resid[(size_t)row * DM + col];
        } else {
            float g = 0.5f * val * (1.0f + erff(val * 0.70710678118654752f));
            outb[(size_t)row * DFFN + col] = f2bf(g);
        }
    }
}

// ---------------- block-causal flash attention v6 (R7 config, exp2 domain) --
__global__ __launch_bounds__(192) void attn6(
    const unsigned short* __restrict__ qkv,   // [ROWS,512] bf16 (q|k), q scaled
    const unsigned short* __restrict__ vT,    // [B,NH,HDIM,SEQ] bf16
    unsigned short* __restrict__ ob)          // [ROWS,DM] bf16
{
    const int sp   = threadIdx.x >> 6;        // split 0..2
    const int lane = threadIdx.x & 63;
    const int qt = 47 - (int)blockIdx.x;      // long blocks first
    const int bh = blockIdx.y;
    const int b = bh >> 3, h = bh & 7;
    const int l15 = lane & 15, l4 = lane >> 4;
    const int q0 = qt * 32;

    __shared__ unsigned short P[3][2][32 * 64];   // 24 KB; [sp] doubles as O park
    __shared__ float sml[3][96];

    const int kend   = ((q0 + 31) / 3) * 3 + 3;
    const int ntiles = (kend + 63) >> 6;
    const int t0 = (ntiles * sp) / 3;
    const int t1 = (ntiles * (sp + 1)) / 3;
    const bool empty = (t0 >= t1);

    float* Osp = (float*)P[sp];               // 32 x OSTR f32 region

    if (empty) {
        #pragma unroll
        for (int i = 0; i < 18; ++i) Osp[lane + i * 64] = 0.f;
        if (lane < 32) { sml[sp][lane] = 0.f; sml[sp][32 + lane] = 0.f; }
    } else {
        const int kendc = min(t1 * 64, kend);
        const int lim_min = (q0 / 3) * 3 + 3;

        bf16x8 qf[2];
        #pragma unroll
        for (int mt = 0; mt < 2; ++mt)
            qf[mt] = *(const bf16x8*)&qkv[((size_t)(b * SEQ + q0 + mt * 16 + l15)) * 512 + h * 32 + l4 * 8];

        const int sw = (l15 & 7) << 3;
        int lim2[2];
        lim2[0] = ((q0 + l15) / 3) * 3 + 3;
        lim2[1] = ((q0 + 16 + l15) / 3) * 3 + 3;

        float lsum[2] = {0.f, 0.f};
        f32x4 of[2][2];
        const f32x4 zf = (f32x4){0.f, 0.f, 0.f, 0.f};
        of[0][0] = zf; of[0][1] = zf; of[1][0] = zf; of[1][1] = zf;

        bf16x8 kf[4];
        #pragma unroll
        for (int kt = 0; kt < 4; ++kt)
            kf[kt] = *(const bf16x8*)&qkv[((size_t)(b * SEQ + t0 * 64 + kt * 16 + l15)) * 512 + 256 + h * 32 + l4 * 8];

        int pb = 0;
        for (int j0 = t0 * 64; j0 < kendc; j0 += 64) {
            f32x4 sf[2][4];
            #pragma unroll
            for (int mt = 0; mt < 2; ++mt)
                #pragma unroll
                for (int kt = 0; kt < 4; ++kt)
                    sf[mt][kt] = __builtin_amdgcn_mfma_f32_16x16x32_bf16(kf[kt], qf[mt], zf, 0, 0, 0);

            const int jn = (j0 + 64 < kendc) ? j0 + 64 : j0;
            bf16x8 kfn[4];
            #pragma unroll
            for (int kt = 0; kt < 4; ++kt)
                kfn[kt] = *(const bf16x8*)&qkv[((size_t)(b * SEQ + jn + kt * 16 + l15)) * 512 + 256 + h * 32 + l4 * 8];
            bf16x8 vf[2][2];
            #pragma unroll
            for (int dh = 0; dh < 2; ++dh)
                #pragma unroll
                for (int ks = 0; ks < 2; ++ks)
                    vf[dh][ks] = *(const bf16x8*)&vT[(((size_t)(b * NH + h)) * HDIM + dh * 16 + l15) * SEQ + j0 + ks * 32 + l4 * 8];

            const bool masked = (j0 + 64 > lim_min);
            #pragma unroll
            for (int mt = 0; mt < 2; ++mt) {
                const int rowq = mt * 16 + l15;
                float ls = 0.f;
                #pragma unroll
                for (int kt = 0; kt < 4; ++kt) {
                    float s0 = sf[mt][kt][0], s1 = sf[mt][kt][1];
                    float s2 = sf[mt][kt][2], s3 = sf[mt][kt][3];
                    if (masked) {
                        const int kb = j0 + kt * 16 + l4 * 4;
                        const int L = lim2[mt];
                        s0 = (kb     < L) ? s0 : -INFINITY;
                        s1 = (kb + 1 < L) ? s1 : -INFINITY;
                        s2 = (kb + 2 < L) ? s2 : -INFINITY;
                        s3 = (kb + 3 < L) ? s3 : -INFINITY;
                    }
                    float p0 = ex2(s0), p1 = ex2(s1);
                    float p2 = ex2(s2), p3 = ex2(s3);
                    ls += (p0 + p1) + (p2 + p3);
                    bf16x4 pk;
                    pk[0] = (__bf16)p0; pk[1] = (__bf16)p1;
                    pk[2] = (__bf16)p2; pk[3] = (__bf16)p3;
                    *(bf16x4*)&P[sp][pb][rowq * 64 + ((kt * 16 + l4 * 4) ^ sw)] = pk;
                }
                lsum[mt] += ls;
            }

            bf16x8 pf[2][2];
            #pragma unroll
            for (int mt = 0; mt < 2; ++mt) {
                int row = mt * 16 + l15;
                #pragma unroll
                for (int ks = 0; ks < 2; ++ks)
                    pf[mt][ks] = *(const bf16x8*)&P[sp][pb][row * 64 + ((ks * 32 + l4 * 8) ^ sw)];
            }
            #pragma unroll
            for (int mt = 0; mt < 2; ++mt)
                #pragma unroll
                for (int dh = 0; dh < 2; ++dh) {
                    of[mt][dh] = __builtin_amdgcn_mfma_f32_16x16x32_bf16(pf[mt][0], vf[dh][0], of[mt][dh], 0, 0, 0);
                    of[mt][dh] = __builtin_amdgcn_mfma_f32_16x16x32_bf16(pf[mt][1], vf[dh][1], of[mt][dh], 0, 0, 0);
                }
            #pragma unroll
            for (int kt = 0; kt < 4; ++kt) kf[kt] = kfn[kt];
            pb ^= 1;
        }

        int bad = (lsum[0] > 1.0e30f || lsum[1] > 1.0e30f) ? 1 : 0;
        if (__any(bad)) {
            // ---- exact safe re-run with online max (never taken normally) ----
            int lim[2][4];
            float mrow[2][4], lsumO[2][4];
            #pragma unroll
            for (int mt = 0; mt < 2; ++mt) {
                of[mt][0] = zf; of[mt][1] = zf;
                #pragma unroll
                for (int r = 0; r < 4; ++r) {
                    mrow[mt][r] = -INFINITY; lsumO[mt][r] = 0.f;
                    int q = q0 + mt * 16 + l4 * 4 + r;
                    lim[mt][r] = (q / 3) * 3 + 3;
                }
            }
            for (int j0 = t0 * 64; j0 < kendc; j0 += 64) {
                bf16x8 kfs[4];
                #pragma unroll
                for (int kt = 0; kt < 4; ++kt)
                    kfs[kt] = *(const bf16x8*)&qkv[((size_t)(b * SEQ + j0 + kt * 16 + l15)) * 512 + 256 + h * 32 + l4 * 8];
                f32x4 sf[2][4];
                #pragma unroll
                for (int mt = 0; mt < 2; ++mt)
                    #pragma unroll
                    for (int kt = 0; kt < 4; ++kt)
                        sf[mt][kt] = __builtin_amdgcn_mfma_f32_16x16x32_bf16(qf[mt], kfs[kt], zf, 0, 0, 0);
                #pragma unroll
                for (int mt = 0; mt < 2; ++mt) {
                    float alpha[4];
                    #pragma unroll
                    for (int r = 0; r < 4; ++r) {
                        const int L = lim[mt][r]; int jb = j0 + l15;
                        float s0 = (jb      < L) ? sf[mt][0][r] : -INFINITY;
                        float s1 = (jb + 16 < L) ? sf[mt][1][r] : -INFINITY;
                        float s2 = (jb + 32 < L) ? sf[mt][2][r] : -INFINITY;
                        float s3 = (jb + 48 < L) ? sf[mt][3][r] : -INFINITY;
                        float tm = fmaxf(fmaxf(s0, s1), fmaxf(s2, s3));
                        tm = fmaxf(tm, __shfl_xor(tm, 1));
                        tm = fmaxf(tm, __shfl_xor(tm, 2));
                        tm = fmaxf(tm, __shfl_xor(tm, 4));
                        tm = fmaxf(tm, __shfl_xor(tm, 8));
                        float mn = fmaxf(mrow[mt][r], tm);
                        float a  = ex2(mrow[mt][r] - mn);
                        mrow[mt][r] = mn;
                        float p0 = ex2(s0 - mn), p1 = ex2(s1 - mn);
                        float p2 = ex2(s2 - mn), p3 = ex2(s3 - mn);
                        int row = mt * 16 + l4 * 4 + r;
                        int swo = (row & 7) << 3;
                        P[sp][1][(row * 64 +      l15) ^ swo] = f2bf(p0);
                        P[sp][1][(row * 64 + 16 + l15) ^ swo] = f2bf(p1);
                        P[sp][1][(row * 64 + 32 + l15) ^ swo] = f2bf(p2);
                        P[sp][1][(row * 64 + 48 + l15) ^ swo] = f2bf(p3);
                        lsumO[mt][r] = lsumO[mt][r] * a + (p0 + p1) + (p2 + p3);
                        alpha[r] = a;
                    }
                    f32x4 av = (f32x4){alpha[0], alpha[1], alpha[2], alpha[3]};
                    of[mt][0] *= av; of[mt][1] *= av;
                }
                bf16x8 pf[2][2], vf[2][2];
                #pragma unroll
                for (int mt = 0; mt < 2; ++mt) {
                    int row = mt * 16 + l15;
                    int swo = (row & 7) << 3;
                    #pragma unroll
                    for (int ks = 0; ks < 2; ++ks)
                        pf[mt][ks] = *(const bf16x8*)&P[sp][1][(row * 64 + ks * 32 + l4 * 8) ^ swo];
                }
                #pragma unroll
                for (int dh = 0; dh < 2; ++dh)
                    #pragma unroll
                    for (int ks = 0; ks < 2; ++ks)
                        vf[dh][ks] = *(const bf16x8*)&vT[(((size_t)(b * NH + h)) * HDIM + dh * 16 + l15) * SEQ + j0 + ks * 32 + l4 * 8];
                #pragma unroll
                for (int mt = 0; mt < 2; ++mt)
                    #pragma unroll
                    for (int dh = 0; dh < 2; ++dh) {
                        of[mt][dh] = __builtin_amdgcn_mfma_f32_16x16x32_bf16(pf[mt][0], vf[dh][0], of[mt][dh], 0, 0, 0);
                        of[mt][dh] = __builtin_amdgcn_mfma_f32_16x16x32_bf16(pf[mt][1], vf[dh][1], of[mt][dh], 0, 0, 0);
                    }
            }
            #pragma unroll
            for (int mt = 0; mt < 2; ++mt)
                #pragma unroll
                for (int r = 0; r < 4; ++r) {
                    float s = lsumO[mt][r];
                    s += __shfl_xor(s, 1);
                    s += __shfl_xor(s, 2);
                    s += __shfl_xor(s, 4);
                    s += __shfl_xor(s, 8);
                    lsumO[mt][r] = s;
                }
            #pragma unroll
            for (int mt = 0; mt < 2; ++mt)
                #pragma unroll
                for (int dh = 0; dh < 2; ++dh)
                    #pragma unroll
                    for (int r = 0; r < 4; ++r)
                        Osp[(mt * 16 + l4 * 4 + r) * OSTR + dh * 16 + l15] = of[mt][dh][r];
            if (l15 == 0) {
                #pragma unroll
                for (int mt = 0; mt < 2; ++mt)
                    #pragma unroll
                    for (int r = 0; r < 4; ++r) {
                        int row = mt * 16 + l4 * 4 + r;
                        sml[sp][row]      = mrow[mt][r];
                        sml[sp][32 + row] = lsumO[mt][r];
                    }
            }
        } else {
            // ---- fast-path finalize: reduce lane-partial lsum, park O -------
            #pragma unroll
            for (int mt = 0; mt < 2; ++mt) {
                float s = lsum[mt];
                s += __shfl_xor(s, 16);
                s += __shfl_xor(s, 32);
                lsum[mt] = s;
            }
            #pragma unroll
            for (int mt = 0; mt < 2; ++mt)
                #pragma unroll
                for (int dh = 0; dh < 2; ++dh)
                    #pragma unroll
                    for (int r = 0; r < 4; ++r)
                        Osp[(mt * 16 + l4 * 4 + r) * OSTR + dh * 16 + l15] = of[mt][dh][r];
            if (lane < 32) sml[sp][lane] = 0.f;
            if (l4 == 0) {
                sml[sp][32 + l15]      = lsum[0];
                sml[sp][32 + 16 + l15] = lsum[1];
            }
        }
    }

    __syncthreads();

    // ---------------- in-block combine + normalize + write ------------------
    const int t = threadIdx.x;
    if (t < 128) {
        const int row = t >> 2;
        const int seg = (t & 3) * 8;
        float m0 = sml[0][row], l0 = sml[0][32 + row];
        float m1 = sml[1][row], l1 = sml[1][32 + row];
        float m2 = sml[2][row], l2 = sml[2][32 + row];
        float mt = fmaxf(fmaxf(m0, m1), m2);
        float w0 = ex2(m0 - mt), w1 = ex2(m1 - mt), w2 = ex2(m2 - mt);
        float inv = 1.0f / (w0 * l0 + w1 * l1 + w2 * l2);
        const float* O0 = (const float*)P[0];
        const float* O1 = (const float*)P[1];
        const float* O2 = (const float*)P[2];
        union { unsigned short u[8]; uint4 v; } pk;
        #pragma unroll
        for (int j = 0; j < 8; ++j) {
            int idx = row * OSTR + seg + j;
            pk.u[j] = f2bf((w0 * O0[idx] + w1 * O1[idx] + w2 * O2[idx]) * inv);
        }
        *(uint4*)&ob[((size_t)(b * SEQ + q0 + row)) * DM + h * 32 + seg] = pk.v;
    }
}

// ---------------- LayerNorm over D=256 (fallback path only) -----------------
__global__ __launch_bounds__(256) void ln_kernel(
    const float* __restrict__ rin,
    const float* __restrict__ gam, const float* __restrict__ bet,
    float* __restrict__ hout, unsigned short* __restrict__ hbout)
{
    int wv = threadIdx.x >> 6, lane = threadIdx.x & 63;
    int row = blockIdx.x * 4 + wv;
    float4 x = *(const float4*)(rin + (size_t)row * DM + lane * 4);
    float s = x.x + x.y + x.z + x.w;
    #pragma unroll
    for (int m = 1; m < 64; m <<= 1) s += __shfl_xor(s, m);
    float mean = s * (1.0f / 256.0f);
    float d0 = x.x - mean, d1 = x.y - mean, d2 = x.z - mean, d3 = x.w - mean;
    float q = d0 * d0 + d1 * d1 + d2 * d2 + d3 * d3;
    #pragma unroll
    for (int m = 1; m < 64; m <<= 1) q += __shfl_xor(q, m);
    float rstd = rsqrtf(q * (1.0f / 256.0f) + 1e-5f);
    float4 g = *(const float4*)(gam + lane * 4);
    float4 b = *(const float4*)(bet + lane * 4);
    float4 y;
    y.x = d0 * rstd * g.x + b.x;
    y.y = d1 * rstd * g.y + b.y;
    y.z = d2 * rstd * g.z + b.z;
    y.w = d3 * rstd * g.w + b.w;
    *(float4*)(hout + (size_t)row * DM + lane * 4) = y;
    ushort4 hb4;
    hb4.x = f2bf(y.x); hb4.y = f2bf(y.y); hb4.z = f2bf(y.z); hb4.w = f2bf(y.w);
    *(ushort4*)(hbout + (size_t)row * DM + lane * 4) = hb4;
}

extern "C" void kernel_launch(void* const* d_in, const int* in_sizes, int n_in,
                              void* d_out, int out_size, void* d_ws, size_t ws_size,
                              hipStream_t stream) {
    const float* x    = (const float*)d_in[0];
    const float* pe   = (const float*)d_in[1];
    const float* Wqkv = (const float*)d_in[2];
    const float* bqkv = (const float*)d_in[3];
    const float* Wo   = (const float*)d_in[4];
    const float* bo   = (const float*)d_in[5];
    const float* W1   = (const float*)d_in[6];
    const float* b1   = (const float*)d_in[7];
    const float* W2   = (const float*)d_in[8];
    const float* b2   = (const float*)d_in[9];
    const float* ln1g = (const float*)d_in[10];
    const float* ln1b = (const float*)d_in[11];
    const float* ln2g = (const float*)d_in[12];
    const float* ln2b = (const float*)d_in[13];
    float* out = (float*)d_out;

    char* ws = (char*)d_ws;
    float*          h    = (float*)(ws + 0);                    // 6,291,456
    unsigned short* hb   = (unsigned short*)(ws + 6291456);     // 3,145,728
    unsigned short* qkvb = (unsigned short*)(ws + 9437184);     // 6,291,456
    unsigned short* vT   = (unsigned short*)(ws + 15728640);    // 3,145,728
    unsigned short* ob   = (unsigned short*)(ws + 18874368);    // 3,145,728
    float*          rbuf = (float*)(ws + 22020096);             // 6,291,456
    unsigned short* f1b  = (unsigned short*)(ws + 28311552);    // 12,582,912 -> 40,894,464
    unsigned short* WqkvB = (unsigned short*)(ws + 40894464);
    unsigned short* WoB   = (unsigned short*)(ws + 50331648);
    unsigned short* W1B   = (unsigned short*)(ws + 53477376);
    unsigned short* W2B   = (unsigned short*)(ws + 66060288);   // -> 78,643,200

    const bool bw = ws_size >= 78643200u;

    if (bw) {
        w2bf4_kernel<<<9216, 256, 0, stream>>>(
            Wqkv, WqkvB, 2304, Wo, WoB, 768, W1, W1B, 3072, W2, W2B);
    }

    pe_add_kernel<<<1536, 256, 0, stream>>>(x, pe, h, hb);

    for (int l = 0; l < NL; ++l) {
        float* hdst = (l == NL - 1) ? out : h;
        if (bw) {
            gemm3<256, 0><<<dim3(48, 12), 256, 0, stream>>>(
                hb, WqkvB + (size_t)l * 768 * 256, bqkv + l * 768, qkvb, vT);
            attn6<<<dim3(48, 32), 192, 0, stream>>>(qkvb, vT, ob);
            gemm_ln<256, 16><<<384, 256, 0, stream>>>(
                ob, WoB + (size_t)l * 256 * 256, bo + l * 256,
                h, ln1g + l * 256, ln1b + l * 256, h, hb);
            gemm3<256, 2><<<dim3(48, 16), 256, 0, stream>>>(
                hb, W1B + (size_t)l * 1024 * 256, b1 + l * 1024, f1b, nullptr);
            gemm_ln<1024, 16><<<384, 256, 0, stream>>>(
                f1b, W2B + (size_t)l * 256 * 1024, b2 + l * 256,
                h, ln2g + l * 256, ln2b + l * 256, hdst, hb);
        } else {
            gemm2f<256, 0><<<dim3(96, 12), 256, 0, stream>>>(
                hb, Wqkv + (size_t)l * 768 * 256, bqkv + l * 768, nullptr, qkvb, vT, nullptr);
            attn6<<<dim3(48, 32), 192, 0, stream>>>(qkvb, vT, ob);
            gemm2f<256, 1><<<dim3(96, 4), 256, 0, stream>>>(
                ob, Wo + (size_t)l * 256 * 256, bo + l * 256, rbuf, nullptr, nullptr, h);
            ln_kernel<<<1536, 256, 0, stream>>>(rbuf, ln1g + l * 256, ln1b + l * 256, h, hb);
            gemm2f<256, 2><<<dim3(96, 16), 256, 0, stream>>>(
                hb, W1 + (size_t)l * 1024 * 256, b1 + l * 1024, nullptr, f1b, nullptr, nullptr);
            gemm2f<1024, 1><<<dim3(96, 4), 256, 0, stream>>>(
                f1b, W2 + (size_t)l * 256 * 1024, b2 + l * 256, rbuf, nullptr, nullptr, h);
            ln_kernel<<<1536, 256, 0, stream>>>(rbuf, ln2g + l * 256, ln2b + l * 256, hdst, hb);
        }
    }
}

// Round 20
// 1802.957 us; speedup vs baseline: 1.1326x; 1.0823x over previous
//
#include <hip/hip_runtime.h>
#include <math.h>

#define SEQ   1536
#define BATCH 4
#define ROWS  (BATCH*SEQ)   // 6144
#define DM    256
#define NH    8
#define HDIM  32
#define NL    24
#define DFFN  1024
#define OSTR  36            // padded O-park row stride (floats)

// q pre-scale: (1/sqrt(32)) * log2(e)  -> scores arrive in log2 domain
#define QSCALE (0.17677669529663687f * 1.4426950408889634f)

typedef __bf16  bf16x4 __attribute__((ext_vector_type(4)));
typedef __bf16  bf16x8 __attribute__((ext_vector_type(8)));
typedef float   f32x4  __attribute__((ext_vector_type(4)));

__device__ __forceinline__ unsigned short f2bf(float f) {
    union { float f; unsigned int u; } v; v.f = f;
    return (unsigned short)((v.u + 0x7fffu + ((v.u >> 16) & 1u)) >> 16);
}
__device__ __forceinline__ float bf2f(unsigned short u) {
    union { unsigned int i; float f; } v; v.i = ((unsigned int)u) << 16; return v.f;
}
__device__ __forceinline__ float ex2(float x) {
    return __builtin_amdgcn_exp2f(x);   // v_exp_f32: 2^x, exp2(-inf)=0
}

__device__ __forceinline__ void gload16(const void* g, void* l) {
    __builtin_amdgcn_global_load_lds(
        (const __attribute__((address_space(1))) void*)g,
        (__attribute__((address_space(3))) void*)l, 16, 0, 0);
}

// ---------------- fused weight f32 -> bf16 pre-pass (4 segments) ------------
__global__ __launch_bounds__(256) void w2bf4_kernel(
    const float* __restrict__ s0, unsigned short* __restrict__ d0v, int n0,
    const float* __restrict__ s1, unsigned short* __restrict__ d1v, int n1,
    const float* __restrict__ s2, unsigned short* __restrict__ d2v, int n2,
    const float* __restrict__ s3, unsigned short* __restrict__ d3v)
{
    int blk = blockIdx.x;
    const float* src; unsigned short* dst;
    if (blk < n0)                { src = s0; dst = d0v; }
    else if (blk < n0 + n1)      { src = s1; dst = d1v; blk -= n0; }
    else if (blk < n0 + n1 + n2) { src = s2; dst = d2v; blk -= n0 + n1; }
    else                         { src = s3; dst = d3v; blk -= n0 + n1 + n2; }
    int i = (blk * 256 + threadIdx.x) * 8;
    float4 a = *(const float4*)(src + i);
    float4 b = *(const float4*)(src + i + 4);
    union { unsigned short u[8]; uint4 v; } pk;
    pk.u[0] = f2bf(a.x); pk.u[1] = f2bf(a.y); pk.u[2] = f2bf(a.z); pk.u[3] = f2bf(a.w);
    pk.u[4] = f2bf(b.x); pk.u[5] = f2bf(b.y); pk.u[6] = f2bf(b.z); pk.u[7] = f2bf(b.w);
    *(uint4*)(dst + i) = pk.v;
}

// ---------------- positional-embedding add ----------------------------------
__global__ __launch_bounds__(256) void pe_add_kernel(
    const float* __restrict__ x, const float* __restrict__ pe,
    float* __restrict__ h, unsigned short* __restrict__ hb)
{
    int i4  = blockIdx.x * 256 + threadIdx.x;
    int idx = i4 * 4;
    int row = idx >> 8;
    int d   = idx & 255;
    int s   = row % SEQ;
    float4 xv = *(const float4*)(x + idx);
    float4 pv = *(const float4*)(pe + s * DM + d);
    float4 hv;
    hv.x = xv.x + pv.x; hv.y = xv.y + pv.y; hv.z = xv.z + pv.z; hv.w = xv.w + pv.w;
    *(float4*)(h + idx) = hv;
    ushort4 hbv;
    hbv.x = f2bf(hv.x); hbv.y = f2bf(hv.y); hbv.z = f2bf(hv.z); hbv.w = f2bf(hv.w);
    *(ushort4*)(hb + idx) = hbv;
}

// ======================= GEMM v3: 128x64 tile, dbuf, swizzled ================
template<int K, int EPI>
__global__ __launch_bounds__(256) void gemm3(
    const unsigned short* __restrict__ A,
    const unsigned short* __restrict__ W,
    const float* __restrict__ bias,
    unsigned short* __restrict__ outb,
    unsigned short* __restrict__ vT)
{
    __shared__ unsigned short Ash[2][128 * 64];
    __shared__ unsigned short Bsh[2][64 * 64];
    const int m0 = blockIdx.x * 128;
    const int n0 = blockIdx.y * 64;
    const int t  = threadIdx.x;
    const int lane = t & 63;
    const int wv = t >> 6;
    const int wm = wv >> 1, wn = wv & 1;
    const int l15 = lane & 15, l4 = lane >> 4;

    const int ar = lane >> 3;
    const int sx = ((lane & 7) ^ ar) * 8;

    f32x4 acc[4][2];
    #pragma unroll
    for (int i = 0; i < 4; ++i) { acc[i][0] = (f32x4){0,0,0,0}; acc[i][1] = (f32x4){0,0,0,0}; }

    const int NT = K / 64;
    #pragma unroll
    for (int i = 0; i < 4; ++i) {
        int c = wv * 4 + i;
        gload16(&A[(size_t)(m0 + c * 8 + ar) * K + sx], &Ash[0][c * 512]);
    }
    gload16(&W[(size_t)(n0 + wv * 8 + ar) * K + sx],        &Bsh[0][wv * 512]);
    gload16(&W[(size_t)(n0 + (wv + 4) * 8 + ar) * K + sx],  &Bsh[0][(wv + 4) * 512]);
    __syncthreads();

    int cur = 0;
    for (int tt = 0; tt < NT; ++tt) {
        if (tt + 1 < NT) {
            const int k0 = (tt + 1) * 64;
            #pragma unroll
            for (int i = 0; i < 4; ++i) {
                int c = wv * 4 + i;
                gload16(&A[(size_t)(m0 + c * 8 + ar) * K + k0 + sx], &Ash[cur ^ 1][c * 512]);
            }
            gload16(&W[(size_t)(n0 + wv * 8 + ar) * K + k0 + sx],       &Bsh[cur ^ 1][wv * 512]);
            gload16(&W[(size_t)(n0 + (wv + 4) * 8 + ar) * K + k0 + sx], &Bsh[cur ^ 1][(wv + 4) * 512]);
        }
        #pragma unroll
        for (int kk = 0; kk < 2; ++kk) {
            bf16x8 af[4], bfr[2];
            #pragma unroll
            for (int mt = 0; mt < 4; ++mt) {
                int row = wm * 64 + mt * 16 + l15;
                af[mt] = *(const bf16x8*)&Ash[cur][row * 64 + (((kk * 4 + l4) ^ (l15 & 7)) * 8)];
            }
            #pragma unroll
            for (int nt = 0; nt < 2; ++nt) {
                int row = wn * 32 + nt * 16 + l15;
                bfr[nt] = *(const bf16x8*)&Bsh[cur][row * 64 + (((kk * 4 + l4) ^ (l15 & 7)) * 8)];
            }
            #pragma unroll
            for (int mt = 0; mt < 4; ++mt)
                #pragma unroll
                for (int nt = 0; nt < 2; ++nt)
                    acc[mt][nt] = __builtin_amdgcn_mfma_f32_16x16x32_bf16(af[mt], bfr[nt], acc[mt][nt], 0, 0, 0);
        }
        __syncthreads();
        cur ^= 1;
    }

    #pragma unroll
    for (int mt = 0; mt < 4; ++mt)
    #pragma unroll
    for (int nt = 0; nt < 2; ++nt)
    #pragma unroll
    for (int r = 0; r < 4; ++r) {
        int row = m0 + wm * 64 + mt * 16 + l4 * 4 + r;
        int col = n0 + wn * 32 + nt * 16 + l15;
        float val = acc[mt][nt][r] + bias[col];
        if (EPI == 0) {
            if (col < 512) {
                if (col < 256) val *= QSCALE;     // 1/sqrt(HD) * log2(e)
                outb[(size_t)row * 512 + col] = f2bf(val);
            } else {
                int c = col - 512; int hh = c >> 5; int d = c & 31;
                int b = row / SEQ; int s = row - b * SEQ;
                vT[(((size_t)(b * NH + hh)) * HDIM + d) * SEQ + s] = f2bf(val);
            }
        } else {
            float g = 0.5f * val * (1.0f + erff(val * 0.70710678118654752f));
            outb[(size_t)row * DFFN + col] = f2bf(g);
        }
    }
}

// ============ GEMM+LN fused: BM x 256 (full row), dbuf, swizzled =============
template<int K, int BM>
__global__ __launch_bounds__(256) void gemm_ln(
    const unsigned short* __restrict__ A,
    const unsigned short* __restrict__ W,
    const float* __restrict__ bias,
    const float* __restrict__ resid,
    const float* __restrict__ gam, const float* __restrict__ bet,
    float* __restrict__ hout, unsigned short* __restrict__ hbout)
{
    constexpr int MT = BM / 16;
    __shared__ unsigned short Ash[2][BM * 64];
    __shared__ unsigned short Bsh[2][256 * 64];
    __shared__ float red[4][BM][2];
    const int m0 = blockIdx.x * BM;
    const int t  = threadIdx.x;
    const int lane = t & 63;
    const int w  = t >> 6;
    const int l15 = lane & 15, l4 = lane >> 4;
    const int ar = lane >> 3;
    const int sx = ((lane & 7) ^ ar) * 8;

    f32x4 acc[MT][4];
    #pragma unroll
    for (int mt = 0; mt < MT; ++mt)
        #pragma unroll
        for (int nt = 0; nt < 4; ++nt)
            acc[mt][nt] = (f32x4){0,0,0,0};

    const int NT = K / 64;
    if (w < BM / 8)
        gload16(&A[(size_t)(m0 + w * 8 + ar) * K + sx], &Ash[0][w * 512]);
    #pragma unroll
    for (int i = 0; i < 8; ++i) {
        int c = w * 8 + i;
        gload16(&W[(size_t)(c * 8 + ar) * K + sx], &Bsh[0][c * 512]);
    }
    __syncthreads();

    int cur = 0;
    for (int tt = 0; tt < NT; ++tt) {
        if (tt + 1 < NT) {
            const int k0 = (tt + 1) * 64;
            if (w < BM / 8)
                gload16(&A[(size_t)(m0 + w * 8 + ar) * K + k0 + sx], &Ash[cur ^ 1][w * 512]);
            #pragma unroll
            for (int i = 0; i < 8; ++i) {
                int c = w * 8 + i;
                gload16(&W[(size_t)(c * 8 + ar) * K + k0 + sx], &Bsh[cur ^ 1][c * 512]);
            }
        }
        #pragma unroll
        for (int kk = 0; kk < 2; ++kk) {
            bf16x8 af[MT], bfr[4];
            #pragma unroll
            for (int mt = 0; mt < MT; ++mt) {
                int row = mt * 16 + l15;
                af[mt] = *(const bf16x8*)&Ash[cur][row * 64 + (((kk * 4 + l4) ^ (l15 & 7)) * 8)];
            }
            #pragma unroll
            for (int nt = 0; nt < 4; ++nt) {
                int row = w * 64 + nt * 16 + l15;
                bfr[nt] = *(const bf16x8*)&Bsh[cur][row * 64 + (((kk * 4 + l4) ^ (l15 & 7)) * 8)];
            }
            #pragma unroll
            for (int mt = 0; mt < MT; ++mt)
                #pragma unroll
                for (int nt = 0; nt < 4; ++nt)
                    acc[mt][nt] = __builtin_amdgcn_mfma_f32_16x16x32_bf16(af[mt], bfr[nt], acc[mt][nt], 0, 0, 0);
        }
        __syncthreads();
        cur ^= 1;
    }

    float vals[MT][4][4];
    float gc[4], bc[4];
    #pragma unroll
    for (int nt = 0; nt < 4; ++nt) {
        int col = w * 64 + nt * 16 + l15;
        gc[nt] = gam[col];
        bc[nt] = bet[col];
    }
    #pragma unroll
    for (int mt = 0; mt < MT; ++mt)
        #pragma unroll
        for (int r = 0; r < 4; ++r) {
            int rowl = mt * 16 + l4 * 4 + r;
            float s = 0.f, s2 = 0.f;
            #pragma unroll
            for (int nt = 0; nt < 4; ++nt) {
                int col = w * 64 + nt * 16 + l15;
                float v = acc[mt][nt][r] + bias[col]
                        + resid[(size_t)(m0 + rowl) * DM + col];
                vals[mt][nt][r] = v;
                s += v; s2 += v * v;
            }
            s  += __shfl_xor(s, 1);  s2 += __shfl_xor(s2, 1);
            s  += __shfl_xor(s, 2);  s2 += __shfl_xor(s2, 2);
            s  += __shfl_xor(s, 4);  s2 += __shfl_xor(s2, 4);
            s  += __shfl_xor(s, 8);  s2 += __shfl_xor(s2, 8);
            if (l15 == 0) { red[w][rowl][0] = s; red[w][rowl][1] = s2; }
        }
    __syncthreads();

    #pragma unroll
    for (int mt = 0; mt < MT; ++mt)
        #pragma unroll
        for (int r = 0; r < 4; ++r) {
            int rowl = mt * 16 + l4 * 4 + r;
            float tot  = red[0][rowl][0] + red[1][rowl][0] + red[2][rowl][0] + red[3][rowl][0];
            float tot2 = red[0][rowl][1] + red[1][rowl][1] + red[2][rowl][1] + red[3][rowl][1];
            float mean = tot * (1.0f / 256.0f);
            float var  = tot2 * (1.0f / 256.0f) - mean * mean;
            float rstd = rsqrtf(var + 1e-5f);
            size_t base = (size_t)(m0 + rowl) * DM;
            #pragma unroll
            for (int nt = 0; nt < 4; ++nt) {
                int col = w * 64 + nt * 16 + l15;
                float y = (vals[mt][nt][r] - mean) * rstd * gc[nt] + bc[nt];
                hout[base + col]  = y;
                hbout[base + col] = f2bf(y);
            }
        }
}

// ---------------- legacy single-buffer GEMM (f32 weights fallback) ----------
template<int K, int EPI>
__global__ __launch_bounds__(256) void gemm2f(
    const unsigned short* __restrict__ A,
    const float* __restrict__ W,
    const float* __restrict__ bias,
    float* __restrict__ outf,
    unsigned short* __restrict__ outb,
    unsigned short* __restrict__ vT,
    const float* __restrict__ resid)
{
    __shared__ unsigned short Ash[64 * 64];
    __shared__ unsigned short Bsh[64 * 64];
    const int m0 = blockIdx.x * 64;
    const int n0 = blockIdx.y * 64;
    const int t  = threadIdx.x;
    const int lane = t & 63;
    const int wv = t >> 6;
    const int wm = wv >> 1, wn = wv & 1;
    const int l15 = lane & 15, l4 = lane >> 4;
    const int ar = lane >> 3;
    const int ac = (lane & 7) * 8;
    const int c0 = wv, c1 = wv + 4;

    f32x4 acc[2][2];
    #pragma unroll
    for (int i = 0; i < 2; ++i) { acc[i][0] = (f32x4){0,0,0,0}; acc[i][1] = (f32x4){0,0,0,0}; }

    for (int k0 = 0; k0 < K; k0 += 64) {
        gload16(&A[(size_t)(m0 + c0 * 8 + ar) * K + k0 + ac], &Ash[c0 * 512]);
        gload16(&A[(size_t)(m0 + c1 * 8 + ar) * K + k0 + ac], &Ash[c1 * 512]);
        {
            int row = t >> 2, seg = (t & 3) * 16;
            const float* gw = W + (size_t)(n0 + row) * K + k0 + seg;
            float4 w0 = *(const float4*)(gw);
            float4 w1 = *(const float4*)(gw + 4);
            float4 w2 = *(const float4*)(gw + 8);
            float4 w3 = *(const float4*)(gw + 12);
            union { unsigned short u[8]; uint4 v; } p0, p1;
            p0.u[0] = f2bf(w0.x); p0.u[1] = f2bf(w0.y); p0.u[2] = f2bf(w0.z); p0.u[3] = f2bf(w0.w);
            p0.u[4] = f2bf(w1.x); p0.u[5] = f2bf(w1.y); p0.u[6] = f2bf(w1.z); p0.u[7] = f2bf(w1.w);
            p1.u[0] = f2bf(w2.x); p1.u[1] = f2bf(w2.y); p1.u[2] = f2bf(w2.z); p1.u[3] = f2bf(w2.w);
            p1.u[4] = f2bf(w3.x); p1.u[5] = f2bf(w3.y); p1.u[6] = f2bf(w3.z); p1.u[7] = f2bf(w3.w);
            *(uint4*)&Bsh[row * 64 + seg] = p0.v;
            *(uint4*)&Bsh[row * 64 + seg + 8] = p1.v;
        }
        __syncthreads();
        #pragma unroll
        for (int kk = 0; kk < 2; ++kk) {
            bf16x8 af[2], bfr[2];
            #pragma unroll
            for (int mt = 0; mt < 2; ++mt)
                af[mt] = *(const bf16x8*)&Ash[(wm * 32 + mt * 16 + l15) * 64 + kk * 32 + l4 * 8];
            #pragma unroll
            for (int nt = 0; nt < 2; ++nt)
                bfr[nt] = *(const bf16x8*)&Bsh[(wn * 32 + nt * 16 + l15) * 64 + kk * 32 + l4 * 8];
            #pragma unroll
            for (int mt = 0; mt < 2; ++mt)
                #pragma unroll
                for (int nt = 0; nt < 2; ++nt)
                    acc[mt][nt] = __builtin_amdgcn_mfma_f32_16x16x32_bf16(af[mt], bfr[nt], acc[mt][nt], 0, 0, 0);
        }
        __syncthreads();
    }

    #pragma unroll
    for (int mt = 0; mt < 2; ++mt)
    #pragma unroll
    for (int nt = 0; nt < 2; ++nt)
    #pragma unroll
    for (int r = 0; r < 4; ++r) {
        int row = m0 + wm * 32 + mt * 16 + l4 * 4 + r;
        int col = n0 + wn * 32 + nt * 16 + l15;
        float val = acc[mt][nt][r] + bias[col];
        if (EPI == 0) {
            if (col < 512) {
                if (col < 256) val *= QSCALE;
                outb[(size_t)row * 512 + col] = f2bf(val);
            } else {
                int c = col - 512; int hh = c >> 5; int d = c & 31;
                int b = row / SEQ; int s = row - b * SEQ;
                vT[(((size_t)(b * NH + hh)) * HDIM + d) * SEQ + s] = f2bf(val);
            }
        } else if (EPI == 1) {
            outf[(size_t)row * DM + col] = val + resid[(size_t)row * DM + col];
        } else {
            float g = 0.5f * val * (1.0f + erff(val * 0.70710678118654752f));
            outb[(size_t)row * DFFN + col] = f2bf(g);
        }
    }
}

// ---------------- block-causal flash attention v6 (R7 config, exp2 domain) --
// XCD-aware block swizzle: all 48 qt-blocks of one (b,h) land on ONE XCD so
// its K/V stream (~192 KB) is fetched into a single L2 instead of up to 8.
__global__ __launch_bounds__(192) void attn6(
    const unsigned short* __restrict__ qkv,   // [ROWS,512] bf16 (q|k), q scaled
    const unsigned short* __restrict__ vT,    // [B,NH,HDIM,SEQ] bf16
    unsigned short* __restrict__ ob)          // [ROWS,DM] bf16
{
    const int sp   = threadIdx.x >> 6;        // split 0..2
    const int lane = threadIdx.x & 63;
    // XCD swizzle (T1): lin -> (xcd, slot); bh groups pinned to one XCD.
    // 1536 blocks % 8 == 0 -> bijective. Long-q blocks first within group.
    const int lin  = (int)blockIdx.x + 48 * (int)blockIdx.y;
    const int xcd  = lin & 7;
    const int slot = lin >> 3;                // 0..191
    const int bh   = xcd + 8 * (slot / 48);   // 4 bh-groups per XCD
    const int qt   = 47 - (slot % 48);        // long blocks first
    const int b = bh >> 3, h = bh & 7;
    const int l15 = lane & 15, l4 = lane >> 4;
    const int q0 = qt * 32;

    __shared__ unsigned short P[3][2][32 * 64];   // 24 KB; [sp] doubles as O park
    __shared__ float sml[3][96];

    const int kend   = ((q0 + 31) / 3) * 3 + 3;
    const int ntiles = (kend + 63) >> 6;
    const int t0 = (ntiles * sp) / 3;
    const int t1 = (ntiles * (sp + 1)) / 3;
    const bool empty = (t0 >= t1);

    float* Osp = (float*)P[sp];               // 32 x OSTR f32 region

    if (empty) {
        #pragma unroll
        for (int i = 0; i < 18; ++i) Osp[lane + i * 64] = 0.f;
        if (lane < 32) { sml[sp][lane] = 0.f; sml[sp][32 + lane] = 0.f; }
    } else {
        const int kendc = min(t1 * 64, kend);
        const int lim_min = (q0 / 3) * 3 + 3;

        bf16x8 qf[2];
        #pragma unroll
        for (int mt = 0; mt < 2; ++mt)
            qf[mt] = *(const bf16x8*)&qkv[((size_t)(b * SEQ + q0 + mt * 16 + l15)) * 512 + h * 32 + l4 * 8];

        const int sw = (l15 & 7) << 3;
        int lim2[2];
        lim2[0] = ((q0 + l15) / 3) * 3 + 3;
        lim2[1] = ((q0 + 16 + l15) / 3) * 3 + 3;

        float lsum[2] = {0.f, 0.f};
        f32x4 of[2][2];
        const f32x4 zf = (f32x4){0.f, 0.f, 0.f, 0.f};
        of[0][0] = zf; of[0][1] = zf; of[1][0] = zf; of[1][1] = zf;

        bf16x8 kf[4];
        #pragma unroll
        for (int kt = 0; kt < 4; ++kt)
            kf[kt] = *(const bf16x8*)&qkv[((size_t)(b * SEQ + t0 * 64 + kt * 16 + l15)) * 512 + 256 + h * 32 + l4 * 8];

        int pb = 0;
        for (int j0 = t0 * 64; j0 < kendc; j0 += 64) {
            f32x4 sf[2][4];
            #pragma unroll
            for (int mt = 0; mt < 2; ++mt)
                #pragma unroll
                for (int kt = 0; kt < 4; ++kt)
                    sf[mt][kt] = __builtin_amdgcn_mfma_f32_16x16x32_bf16(kf[kt], qf[mt], zf, 0, 0, 0);

            const int jn = (j0 + 64 < kendc) ? j0 + 64 : j0;
            bf16x8 kfn[4];
            #pragma unroll
            for (int kt = 0; kt < 4; ++kt)
                kfn[kt] = *(const bf16x8*)&qkv[((size_t)(b * SEQ + jn + kt * 16 + l15)) * 512 + 256 + h * 32 + l4 * 8];
            bf16x8 vf[2][2];
            #pragma unroll
            for (int dh = 0; dh < 2; ++dh)
                #pragma unroll
                for (int ks = 0; ks < 2; ++ks)
                    vf[dh][ks] = *(const bf16x8*)&vT[(((size_t)(b * NH + h)) * HDIM + dh * 16 + l15) * SEQ + j0 + ks * 32 + l4 * 8];

            const bool masked = (j0 + 64 > lim_min);
            #pragma unroll
            for (int mt = 0; mt < 2; ++mt) {
                const int rowq = mt * 16 + l15;
                float ls = 0.f;
                #pragma unroll
                for (int kt = 0; kt < 4; ++kt) {
                    float s0 = sf[mt][kt][0], s1 = sf[mt][kt][1];
                    float s2 = sf[mt][kt][2], s3 = sf[mt][kt][3];
                    if (masked) {
                        const int kb = j0 + kt * 16 + l4 * 4;
                        const int L = lim2[mt];
                        s0 = (kb     < L) ? s0 : -INFINITY;
                        s1 = (kb + 1 < L) ? s1 : -INFINITY;
                        s2 = (kb + 2 < L) ? s2 : -INFINITY;
                        s3 = (kb + 3 < L) ? s3 : -INFINITY;
                    }
                    float p0 = ex2(s0), p1 = ex2(s1);
                    float p2 = ex2(s2), p3 = ex2(s3);
                    ls += (p0 + p1) + (p2 + p3);
                    bf16x4 pk;
                    pk[0] = (__bf16)p0; pk[1] = (__bf16)p1;
                    pk[2] = (__bf16)p2; pk[3] = (__bf16)p3;
                    *(bf16x4*)&P[sp][pb][rowq * 64 + ((kt * 16 + l4 * 4) ^ sw)] = pk;
                }
                lsum[mt] += ls;
            }

            bf16x8 pf[2][2];
            #pragma unroll
            for (int mt = 0; mt < 2; ++mt) {
                int row = mt * 16 + l15;
                #pragma unroll
                for (int ks = 0; ks < 2; ++ks)
                    pf[mt][ks] = *(const bf16x8*)&P[sp][pb][row * 64 + ((ks * 32 + l4 * 8) ^ sw)];
            }
            #pragma unroll
            for (int mt = 0; mt < 2; ++mt)
                #pragma unroll
                for (int dh = 0; dh < 2; ++dh) {
                    of[mt][dh] = __builtin_amdgcn_mfma_f32_16x16x32_bf16(pf[mt][0], vf[dh][0], of[mt][dh], 0, 0, 0);
                    of[mt][dh] = __builtin_amdgcn_mfma_f32_16x16x32_bf16(pf[mt][1], vf[dh][1], of[mt][dh], 0, 0, 0);
                }
            #pragma unroll
            for (int kt = 0; kt < 4; ++kt) kf[kt] = kfn[kt];
            pb ^= 1;
        }

        int bad = (lsum[0] > 1.0e30f || lsum[1] > 1.0e30f) ? 1 : 0;
        if (__any(bad)) {
            // ---- exact safe re-run with online max (never taken normally) ----
            int lim[2][4];
            float mrow[2][4], lsumO[2][4];
            #pragma unroll
            for (int mt = 0; mt < 2; ++mt) {
                of[mt][0] = zf; of[mt][1] = zf;
                #pragma unroll
                for (int r = 0; r < 4; ++r) {
                    mrow[mt][r] = -INFINITY; lsumO[mt][r] = 0.f;
                    int q = q0 + mt * 16 + l4 * 4 + r;
                    lim[mt][r] = (q / 3) * 3 + 3;
                }
            }
            for (int j0 = t0 * 64; j0 < kendc; j0 += 64) {
                bf16x8 kfs[4];
                #pragma unroll
                for (int kt = 0; kt < 4; ++kt)
                    kfs[kt] = *(const bf16x8*)&qkv[((size_t)(b * SEQ + j0 + kt * 16 + l15)) * 512 + 256 + h * 32 + l4 * 8];
                f32x4 sf[2][4];
                #pragma unroll
                for (int mt = 0; mt < 2; ++mt)
                    #pragma unroll
                    for (int kt = 0; kt < 4; ++kt)
                        sf[mt][kt] = __builtin_amdgcn_mfma_f32_16x16x32_bf16(qf[mt], kfs[kt], zf, 0, 0, 0);
                #pragma unroll
                for (int mt = 0; mt < 2; ++mt) {
                    float alpha[4];
                    #pragma unroll
                    for (int r = 0; r < 4; ++r) {
                        const int L = lim[mt][r]; int jb = j0 + l15;
                        float s0 = (jb      < L) ? sf[mt][0][r] : -INFINITY;
                        float s1 = (jb + 16 < L) ? sf[mt][1][r] : -INFINITY;
                        float s2 = (jb + 32 < L) ? sf[mt][2][r] : -INFINITY;
                        float s3 = (jb + 48 < L) ? sf[mt][3][r] : -INFINITY;
                        float tm = fmaxf(fmaxf(s0, s1), fmaxf(s2, s3));
                        tm = fmaxf(tm, __shfl_xor(tm, 1));
                        tm = fmaxf(tm, __shfl_xor(tm, 2));
                        tm = fmaxf(tm, __shfl_xor(tm, 4));
                        tm = fmaxf(tm, __shfl_xor(tm, 8));
                        float mn = fmaxf(mrow[mt][r], tm);
                        float a  = ex2(mrow[mt][r] - mn);
                        mrow[mt][r] = mn;
                        float p0 = ex2(s0 - mn), p1 = ex2(s1 - mn);
                        float p2 = ex2(s2 - mn), p3 = ex2(s3 - mn);
                        int row = mt * 16 + l4 * 4 + r;
                        int swo = (row & 7) << 3;
                        P[sp][1][(row * 64 +      l15) ^ swo] = f2bf(p0);
                        P[sp][1][(row * 64 + 16 + l15) ^ swo] = f2bf(p1);
                        P[sp][1][(row * 64 + 32 + l15) ^ swo] = f2bf(p2);
                        P[sp][1][(row * 64 + 48 + l15) ^ swo] = f2bf(p3);
                        lsumO[mt][r] = lsumO[mt][r] * a + (p0 + p1) + (p2 + p3);
                        alpha[r] = a;
                    }
                    f32x4 av = (f32x4){alpha[0], alpha[1], alpha[2], alpha[3]};
                    of[mt][0] *= av; of[mt][1] *= av;
                }
                bf16x8 pf[2][2], vf[2][2];
                #pragma unroll
                for (int mt = 0; mt < 2; ++mt) {
                    int row = mt * 16 + l15;
                    int swo = (row & 7) << 3;
                    #pragma unroll
                    for (int ks = 0; ks < 2; ++ks)
                        pf[mt][ks] = *(const bf16x8*)&P[sp][1][(row * 64 + ks * 32 + l4 * 8) ^ swo];
                }
                #pragma unroll
                for (int dh = 0; dh < 2; ++dh)
                    #pragma unroll
                    for (int ks = 0; ks < 2; ++ks)
                        vf[dh][ks] = *(const bf16x8*)&vT[(((size_t)(b * NH + h)) * HDIM + dh * 16 + l15) * SEQ + j0 + ks * 32 + l4 * 8];
                #pragma unroll
                for (int mt = 0; mt < 2; ++mt)
                    #pragma unroll
                    for (int dh = 0; dh < 2; ++dh) {
                        of[mt][dh] = __builtin_amdgcn_mfma_f32_16x16x32_bf16(pf[mt][0], vf[dh][0], of[mt][dh], 0, 0, 0);
                        of[mt][dh] = __builtin_amdgcn_mfma_f32_16x16x32_bf16(pf[mt][1], vf[dh][1], of[mt][dh], 0, 0, 0);
                    }
            }
            #pragma unroll
            for (int mt = 0; mt < 2; ++mt)
                #pragma unroll
                for (int r = 0; r < 4; ++r) {
                    float s = lsumO[mt][r];
                    s += __shfl_xor(s, 1);
                    s += __shfl_xor(s, 2);
                    s += __shfl_xor(s, 4);
                    s += __shfl_xor(s, 8);
                    lsumO[mt][r] = s;
                }
            #pragma unroll
            for (int mt = 0; mt < 2; ++mt)
                #pragma unroll
                for (int dh = 0; dh < 2; ++dh)
                    #pragma unroll
                    for (int r = 0; r < 4; ++r)
                        Osp[(mt * 16 + l4 * 4 + r) * OSTR + dh * 16 + l15] = of[mt][dh][r];
            if (l15 == 0) {
                #pragma unroll
                for (int mt = 0; mt < 2; ++mt)
                    #pragma unroll
                    for (int r = 0; r < 4; ++r) {
                        int row = mt * 16 + l4 * 4 + r;
                        sml[sp][row]      = mrow[mt][r];
                        sml[sp][32 + row] = lsumO[mt][r];
                    }
            }
        } else {
            // ---- fast-path finalize: reduce lane-partial lsum, park O -------
            #pragma unroll
            for (int mt = 0; mt < 2; ++mt) {
                float s = lsum[mt];
                s += __shfl_xor(s, 16);
                s += __shfl_xor(s, 32);
                lsum[mt] = s;
            }
            #pragma unroll
            for (int mt = 0; mt < 2; ++mt)
                #pragma unroll
                for (int dh = 0; dh < 2; ++dh)
                    #pragma unroll
                    for (int r = 0; r < 4; ++r)
                        Osp[(mt * 16 + l4 * 4 + r) * OSTR + dh * 16 + l15] = of[mt][dh][r];
            if (lane < 32) sml[sp][lane] = 0.f;
            if (l4 == 0) {
                sml[sp][32 + l15]      = lsum[0];
                sml[sp][32 + 16 + l15] = lsum[1];
            }
        }
    }

    __syncthreads();

    // ---------------- in-block combine + normalize + write ------------------
    const int t = threadIdx.x;
    if (t < 128) {
        const int row = t >> 2;
        const int seg = (t & 3) * 8;
        float m0 = sml[0][row], l0 = sml[0][32 + row];
        float m1 = sml[1][row], l1 = sml[1][32 + row];
        float m2 = sml[2][row], l2 = sml[2][32 + row];
        float mt = fmaxf(fmaxf(m0, m1), m2);
        float w0 = ex2(m0 - mt), w1 = ex2(m1 - mt), w2 = ex2(m2 - mt);
        float inv = 1.0f / (w0 * l0 + w1 * l1 + w2 * l2);
        const float* O0 = (const float*)P[0];
        const float* O1 = (const float*)P[1];
        const float* O2 = (const float*)P[2];
        union { unsigned short u[8]; uint4 v; } pk;
        #pragma unroll
        for (int j = 0; j < 8; ++j) {
            int idx = row * OSTR + seg + j;
            pk.u[j] = f2bf((w0 * O0[idx] + w1 * O1[idx] + w2 * O2[idx]) * inv);
        }
        *(uint4*)&ob[((size_t)(b * SEQ + q0 + row)) * DM + h * 32 + seg] = pk.v;
    }
}

// ---------------- LayerNorm over D=256 (fallback path only) -----------------
__global__ __launch_bounds__(256) void ln_kernel(
    const float* __restrict__ rin,
    const float* __restrict__ gam, const float* __restrict__ bet,
    float* __restrict__ hout, unsigned short* __restrict__ hbout)
{
    int wv = threadIdx.x >> 6, lane = threadIdx.x & 63;
    int row = blockIdx.x * 4 + wv;
    float4 x = *(const float4*)(rin + (size_t)row * DM + lane * 4);
    float s = x.x + x.y + x.z + x.w;
    #pragma unroll
    for (int m = 1; m < 64; m <<= 1) s += __shfl_xor(s, m);
    float mean = s * (1.0f / 256.0f);
    float d0 = x.x - mean, d1 = x.y - mean, d2 = x.z - mean, d3 = x.w - mean;
    float q = d0 * d0 + d1 * d1 + d2 * d2 + d3 * d3;
    #pragma unroll
    for (int m = 1; m < 64; m <<= 1) q += __shfl_xor(q, m);
    float rstd = rsqrtf(q * (1.0f / 256.0f) + 1e-5f);
    float4 g = *(const float4*)(gam + lane * 4);
    float4 b = *(const float4*)(bet + lane * 4);
    float4 y;
    y.x = d0 * rstd * g.x + b.x;
    y.y = d1 * rstd * g.y + b.y;
    y.z = d2 * rstd * g.z + b.z;
    y.w = d3 * rstd * g.w + b.w;
    *(float4*)(hout + (size_t)row * DM + lane * 4) = y;
    ushort4 hb4;
    hb4.x = f2bf(y.x); hb4.y = f2bf(y.y); hb4.z = f2bf(y.z); hb4.w = f2bf(y.w);
    *(ushort4*)(hbout + (size_t)row * DM + lane * 4) = hb4;
}

extern "C" void kernel_launch(void* const* d_in, const int* in_sizes, int n_in,
                              void* d_out, int out_size, void* d_ws, size_t ws_size,
                              hipStream_t stream) {
    const float* x    = (const float*)d_in[0];
    const float* pe   = (const float*)d_in[1];
    const float* Wqkv = (const float*)d_in[2];
    const float* bqkv = (const float*)d_in[3];
    const float* Wo   = (const float*)d_in[4];
    const float* bo   = (const float*)d_in[5];
    const float* W1   = (const float*)d_in[6];
    const float* b1   = (const float*)d_in[7];
    const float* W2   = (const float*)d_in[8];
    const float* b2   = (const float*)d_in[9];
    const float* ln1g = (const float*)d_in[10];
    const float* ln1b = (const float*)d_in[11];
    const float* ln2g = (const float*)d_in[12];
    const float* ln2b = (const float*)d_in[13];
    float* out = (float*)d_out;

    char* ws = (char*)d_ws;
    float*          h    = (float*)(ws + 0);                    // 6,291,456
    unsigned short* hb   = (unsigned short*)(ws + 6291456);     // 3,145,728
    unsigned short* qkvb = (unsigned short*)(ws + 9437184);     // 6,291,456
    unsigned short* vT   = (unsigned short*)(ws + 15728640);    // 3,145,728
    unsigned short* ob   = (unsigned short*)(ws + 18874368);    // 3,145,728
    float*          rbuf = (float*)(ws + 22020096);             // 6,291,456
    unsigned short* f1b  = (unsigned short*)(ws + 28311552);    // 12,582,912 -> 40,894,464
    unsigned short* WqkvB = (unsigned short*)(ws + 40894464);
    unsigned short* WoB   = (unsigned short*)(ws + 50331648);
    unsigned short* W1B   = (unsigned short*)(ws + 53477376);
    unsigned short* W2B   = (unsigned short*)(ws + 66060288);   // -> 78,643,200

    const bool bw = ws_size >= 78643200u;

    if (bw) {
        w2bf4_kernel<<<9216, 256, 0, stream>>>(
            Wqkv, WqkvB, 2304, Wo, WoB, 768, W1, W1B, 3072, W2, W2B);
    }

    pe_add_kernel<<<1536, 256, 0, stream>>>(x, pe, h, hb);

    for (int l = 0; l < NL; ++l) {
        float* hdst = (l == NL - 1) ? out : h;
        if (bw) {
            gemm3<256, 0><<<dim3(48, 12), 256, 0, stream>>>(
                hb, WqkvB + (size_t)l * 768 * 256, bqkv + l * 768, qkvb, vT);
            attn6<<<dim3(48, 32), 192, 0, stream>>>(qkvb, vT, ob);
            gemm_ln<256, 16><<<384, 256, 0, stream>>>(
                ob, WoB + (size_t)l * 256 * 256, bo + l * 256,
                h, ln1g + l * 256, ln1b + l * 256, h, hb);
            gemm3<256, 2><<<dim3(48, 16), 256, 0, stream>>>(
                hb, W1B + (size_t)l * 1024 * 256, b1 + l * 1024, f1b, nullptr);
            gemm_ln<1024, 16><<<384, 256, 0, stream>>>(
                f1b, W2B + (size_t)l * 256 * 1024, b2 + l * 256,
                h, ln2g + l * 256, ln2b + l * 256, hdst, hb);
        } else {
            gemm2f<256, 0><<<dim3(96, 12), 256, 0, stream>>>(
                hb, Wqkv + (size_t)l * 768 * 256, bqkv + l * 768, nullptr, qkvb, vT, nullptr);
            attn6<<<dim3(48, 32), 192, 0, stream>>>(qkvb, vT, ob);
            gemm2f<256, 1><<<dim3(96, 4), 256, 0, stream>>>(
                ob, Wo + (size_t)l * 256 * 256, bo + l * 256, rbuf, nullptr, nullptr, h);
            ln_kernel<<<1536, 256, 0, stream>>>(rbuf, ln1g + l * 256, ln1b + l * 256, h, hb);
            gemm2f<256, 2><<<dim3(96, 16), 256, 0, stream>>>(
                hb, W1 + (size_t)l * 1024 * 256, b1 + l * 1024, nullptr, f1b, nullptr, nullptr);
            gemm2f<1024, 1><<<dim3(96, 4), 256, 0, stream>>>(
                f1b, W2 + (size_t)l * 256 * 1024, b2 + l * 256, rbuf, nullptr, nullptr, h);
            ln_kernel<<<1536, 256, 0, stream>>>(rbuf, ln2g + l * 256, ln2b + l * 256, hdst, hb);
        }
    }
}